// Round 1
// baseline (256.366 us; speedup 1.0000x reference)
//
#include <hip/hip_runtime.h>
#include <hip/hip_bf16.h>
#include <math.h>

// ---------------- problem constants ----------------
#define T_TOK 4096
#define D_DIM 1024
#define I_DIM 512
#define E_EXP 8
#define KSEL 2
#define NPAIR (T_TOK * KSEL)          // 8192
#define ROUTED_CAP 9216               // >= 8192 + 8*127, multiple of 128
#define SHARED_BASE ROUTED_CAP        // 9216
#define RTOT (ROUTED_CAP + T_TOK)     // 13312
#define MAXTILES 104                  // <= 71 routed + 32 shared + slack

typedef __bf16 bf16x8 __attribute__((ext_vector_type(8)));
typedef float f32x4 __attribute__((ext_vector_type(4)));
typedef unsigned short ushort8 __attribute__((ext_vector_type(8)));

// ---------------- scratch layout (bytes) ----------------
constexpr size_t SZ_XB  = (size_t)T_TOK * D_DIM * 2;        // 8.39 MB
constexpr size_t SZ_WT  = (size_t)E_EXP * D_DIM * I_DIM * 2;// 8.39 MB each
constexpr size_t SZ_SWT = (size_t)D_DIM * I_DIM * 2;        // 1.05 MB each
constexpr size_t SZ_H   = (size_t)RTOT * I_DIM * 2;         // 13.6 MB
constexpr size_t SZ_Y   = (size_t)RTOT * D_DIM * 2;         // 27.3 MB

constexpr size_t OFF_XB   = 0;
constexpr size_t OFF_UT   = OFF_XB  + SZ_XB;
constexpr size_t OFF_GT   = OFF_UT  + SZ_WT;
constexpr size_t OFF_DT   = OFF_GT  + SZ_WT;
constexpr size_t OFF_SUT  = OFF_DT  + SZ_WT;
constexpr size_t OFF_SGT  = OFF_SUT + SZ_SWT;
constexpr size_t OFF_SDT  = OFF_SGT + SZ_SWT;
constexpr size_t OFF_H    = OFF_SDT + SZ_SWT;
constexpr size_t OFF_Y    = OFF_H   + SZ_H;
constexpr size_t OFF_TOPKI= OFF_Y   + SZ_Y;                 // NPAIR int
constexpr size_t OFF_TOPKW= OFF_TOPKI + (size_t)NPAIR * 4;  // NPAIR float
constexpr size_t OFF_INV  = OFF_TOPKW + (size_t)NPAIR * 4;  // NPAIR int
constexpr size_t OFF_PERM = OFF_INV   + (size_t)NPAIR * 4;  // RTOT int
constexpr size_t OFF_CNT  = OFF_PERM  + (size_t)RTOT * 4;   // 8 int (zeroed)
constexpr size_t OFF_CUR  = OFF_CNT   + 32;                 // 8 int (zeroed)
constexpr size_t OFF_OFFS = OFF_CUR   + 32;                 // 8 int
constexpr size_t OFF_META = OFF_OFFS  + 64;                 // MAXTILES * int2

// ---------------- helpers ----------------
__device__ __forceinline__ unsigned short f2bf(float f) {
  unsigned int u = __float_as_uint(f);
  unsigned int r = (u + 0x7FFFu + ((u >> 16) & 1u)) >> 16;
  return (unsigned short)r;
}
__device__ __forceinline__ float bf2f(unsigned short s) {
  return __uint_as_float(((unsigned int)s) << 16);
}
__device__ __forceinline__ void gload_lds16(const void* g, void* l) {
  __builtin_amdgcn_global_load_lds(
      (const __attribute__((address_space(1))) void*)g,
      (__attribute__((address_space(3))) void*)l, 16, 0, 0);
}

// ---------------- 1) x fp32 -> bf16 ----------------
__global__ void cvt_x_kernel(const float* __restrict__ in, unsigned short* __restrict__ out) {
  int g = blockIdx.x * blockDim.x + threadIdx.x;   // n/8 threads
  const float4* p = (const float4*)in;
  float4 a = p[2 * g], b = p[2 * g + 1];
  ushort8 o;
  o[0] = f2bf(a.x); o[1] = f2bf(a.y); o[2] = f2bf(a.z); o[3] = f2bf(a.w);
  o[4] = f2bf(b.x); o[5] = f2bf(b.y); o[6] = f2bf(b.z); o[7] = f2bf(b.w);
  ((ushort8*)out)[g] = o;
}

// ---------------- 2) transpose-convert [R][C] fp32 -> [C][R] bf16 (batched) ----
__global__ void transpose_cvt_kernel(const float* __restrict__ in, unsigned short* __restrict__ out,
                                     int R, int C) {
  __shared__ float t[32][33];
  size_t bo = (size_t)blockIdx.z * R * C;
  in  += bo; out += bo;
  int c0 = blockIdx.x * 32, r0 = blockIdx.y * 32;
  int tx = threadIdx.x, ty = threadIdx.y;          // block (32,8)
#pragma unroll
  for (int i = 0; i < 4; ++i)
    t[ty + 8 * i][tx] = in[(size_t)(r0 + ty + 8 * i) * C + c0 + tx];
  __syncthreads();
#pragma unroll
  for (int i = 0; i < 4; ++i)
    out[(size_t)(c0 + ty + 8 * i) * R + r0 + tx] = f2bf(t[tx][ty + 8 * i]);
}

// ---------------- 3) gating: logits, top-2, renorm, counts ----------------
__global__ void gating_kernel(const float* __restrict__ x, const float* __restrict__ gw,
                              int* __restrict__ topk_idx, float* __restrict__ topk_w,
                              int* __restrict__ counts) {
  int lane = threadIdx.x & 63;
  int t = blockIdx.x * 4 + (threadIdx.x >> 6);     // wave per token
  const float4* xr = (const float4*)(x + (size_t)t * D_DIM);
  float4 xv[4];
#pragma unroll
  for (int j = 0; j < 4; ++j) xv[j] = xr[lane + 64 * j];
  float l[E_EXP];
#pragma unroll
  for (int e = 0; e < E_EXP; ++e) {
    const float4* gr = (const float4*)(gw + (size_t)e * D_DIM);
    float acc = 0.f;
#pragma unroll
    for (int j = 0; j < 4; ++j) {
      float4 g = gr[lane + 64 * j];
      acc += xv[j].x * g.x + xv[j].y * g.y + xv[j].z * g.z + xv[j].w * g.w;
    }
#pragma unroll
    for (int off = 32; off; off >>= 1) acc += __shfl_xor(acc, off, 64);
    l[e] = acc;
  }
  if (lane == 0) {
    int i0 = 0; float m0 = l[0];
#pragma unroll
    for (int e = 1; e < E_EXP; ++e) if (l[e] > m0) { m0 = l[e]; i0 = e; }
    int i1 = -1; float m1 = -1e30f;
#pragma unroll
    for (int e = 0; e < E_EXP; ++e) if (e != i0 && l[e] > m1) { m1 = l[e]; i1 = e; }
    // renormalized top-2 softmax (global softmax denominator cancels)
    float e1 = __expf(m1 - m0);
    float w0 = 1.0f / (1.0f + e1);
    float w1 = e1 / (1.0f + e1);
    topk_idx[2 * t] = i0; topk_idx[2 * t + 1] = i1;
    topk_w[2 * t] = w0;   topk_w[2 * t + 1] = w1;
    atomicAdd(&counts[i0], 1);
    atomicAdd(&counts[i1], 1);
  }
}

// ---------------- 4) plan: segment offsets, tile table, pad fill ----------------
__global__ void plan_kernel(const int* __restrict__ counts, int* __restrict__ offs,
                            int* __restrict__ meta, int* __restrict__ perm) {
  __shared__ int so[E_EXP], sc[E_EXP];
  int tid = threadIdx.x;
  if (tid == 0) {
    int o = 0, tc = 0;
    int2* m2 = (int2*)meta;
    for (int e = 0; e < E_EXP; ++e) {
      int c = counts[e];
      so[e] = o; sc[e] = c; offs[e] = o;
      int pt = (c + 127) >> 7;
      for (int ti = 0; ti < pt; ++ti) m2[tc++] = make_int2(e, o + ti * 128);
      o += pt * 128;
    }
    for (int ti = 0; ti < T_TOK / 128; ++ti)
      m2[tc++] = make_int2(E_EXP, SHARED_BASE + ti * 128);
    for (; tc < MAXTILES; ++tc) m2[tc] = make_int2(-1, 0);
  }
  __syncthreads();
  for (int p = tid; p < E_EXP * 128; p += 256) {   // pad rows -> token 0
    int e = p >> 7, s = p & 127;
    int c = sc[e];
    int padn = (((c + 127) >> 7) << 7) - c;
    if (s < padn) perm[so[e] + c + s] = 0;
  }
}

// ---------------- 5) scatter: perm + inv ----------------
__global__ void scatter_kernel(const int* __restrict__ tidx, const int* __restrict__ offs,
                               int* __restrict__ cursor, int* __restrict__ perm,
                               int* __restrict__ inv) {
  int g = blockIdx.x * 256 + threadIdx.x;
  if (g < NPAIR) {
    int e = tidx[g];
    int pos = atomicAdd(&cursor[e], 1);
    int row = offs[e] + pos;
    perm[row] = g >> 1;
    inv[g] = row;
  } else if (g < NPAIR + T_TOK) {
    int t = g - NPAIR;
    perm[SHARED_BASE + t] = t;
  }
}

// ---------------- 6) GEMM1: H = (Xg @ U) * gelu(Xg @ G), bf16 MFMA ----------------
__global__ __launch_bounds__(256, 2) void gemm1_kernel(
    const unsigned short* __restrict__ xb, const unsigned short* __restrict__ Ut,
    const unsigned short* __restrict__ Gt, const unsigned short* __restrict__ sUt,
    const unsigned short* __restrict__ sGt, unsigned short* __restrict__ H,
    const int* __restrict__ meta, const int* __restrict__ perm) {
  int2 m2 = ((const int2*)meta)[blockIdx.x];
  int e = m2.x;
  if (e < 0) return;
  int base = m2.y;
  int n0 = blockIdx.y * 128;
  const unsigned short* BU = (e < E_EXP) ? Ut + (size_t)e * I_DIM * D_DIM : sUt;
  const unsigned short* BG = (e < E_EXP) ? Gt + (size_t)e * I_DIM * D_DIM : sGt;

  __shared__ unsigned short As[128 * 32];
  __shared__ unsigned short BUs[128 * 32];
  __shared__ unsigned short BGs[128 * 32];

  int tid = threadIdx.x;
  int lane = tid & 63, wv = tid >> 6;
  int c0 = tid, c1 = tid + 256;                    // 16B chunk ids (512 total/array)
  int am0 = c0 >> 2, ak0 = (c0 & 3) * 8;
  int am1 = c1 >> 2, ak1 = (c1 & 3) * 8;
  int tok0 = perm[base + am0];
  int tok1 = perm[base + am1];
  const unsigned short* ga0 = xb + (size_t)tok0 * D_DIM + ak0;
  const unsigned short* ga1 = xb + (size_t)tok1 * D_DIM + ak1;
  const unsigned short* gu0 = BU + (size_t)(n0 + am0) * D_DIM + ak0;
  const unsigned short* gu1 = BU + (size_t)(n0 + am1) * D_DIM + ak1;
  const unsigned short* gg0 = BG + (size_t)(n0 + am0) * D_DIM + ak0;
  const unsigned short* gg1 = BG + (size_t)(n0 + am1) * D_DIM + ak1;
  unsigned short* lA0 = As  + wv * 512;  unsigned short* lA1 = As  + 2048 + wv * 512;
  unsigned short* lU0 = BUs + wv * 512;  unsigned short* lU1 = BUs + 2048 + wv * 512;
  unsigned short* lG0 = BGs + wv * 512;  unsigned short* lG1 = BGs + 2048 + wv * 512;

  f32x4 accU[4][4] = {};
  f32x4 accG[4][4] = {};
  int wr = (wv >> 1) * 64, wc = (wv & 1) * 64;
  int l15 = lane & 15, l4 = lane >> 4;

  for (int k0 = 0; k0 < D_DIM; k0 += 32) {
    gload_lds16(ga0 + k0, lA0); gload_lds16(ga1 + k0, lA1);
    gload_lds16(gu0 + k0, lU0); gload_lds16(gu1 + k0, lU1);
    gload_lds16(gg0 + k0, lG0); gload_lds16(gg1 + k0, lG1);
    __syncthreads();
    bf16x8 af[4], uf[4], gf[4];
#pragma unroll
    for (int i = 0; i < 4; ++i) {
      af[i] = *reinterpret_cast<const bf16x8*>(&As [(wr + i * 16 + l15) * 32 + l4 * 8]);
      uf[i] = *reinterpret_cast<const bf16x8*>(&BUs[(wc + i * 16 + l15) * 32 + l4 * 8]);
      gf[i] = *reinterpret_cast<const bf16x8*>(&BGs[(wc + i * 16 + l15) * 32 + l4 * 8]);
    }
#pragma unroll
    for (int i = 0; i < 4; ++i)
#pragma unroll
      for (int j = 0; j < 4; ++j) {
        accU[i][j] = __builtin_amdgcn_mfma_f32_16x16x32_bf16(af[i], uf[j], accU[i][j], 0, 0, 0);
        accG[i][j] = __builtin_amdgcn_mfma_f32_16x16x32_bf16(af[i], gf[j], accG[i][j], 0, 0, 0);
      }
    __syncthreads();
  }

  const float is2 = 0.70710678118654752f;
#pragma unroll
  for (int i = 0; i < 4; ++i) {
    int row = base + wr + i * 16 + l4 * 4;
#pragma unroll
    for (int j = 0; j < 4; ++j) {
      int col = n0 + wc + j * 16 + l15;
#pragma unroll
      for (int r = 0; r < 4; ++r) {
        float u = accU[i][j][r], g = accG[i][j][r];
        float gl = 0.5f * g * (1.0f + erff(g * is2));
        H[(size_t)(row + r) * I_DIM + col] = f2bf(u * gl);
      }
    }
  }
}

// ---------------- 7) GEMM2: Y = H @ Down, bf16 MFMA ----------------
__global__ __launch_bounds__(256, 2) void gemm2_kernel(
    const unsigned short* __restrict__ H, const unsigned short* __restrict__ Dt,
    const unsigned short* __restrict__ sDt, unsigned short* __restrict__ Y,
    const int* __restrict__ meta) {
  int2 m2 = ((const int2*)meta)[blockIdx.x];
  int e = m2.x;
  if (e < 0) return;
  int base = m2.y;
  int n0 = blockIdx.y * 128;
  const unsigned short* B = (e < E_EXP) ? Dt + (size_t)e * D_DIM * I_DIM : sDt;

  __shared__ unsigned short As[128 * 32];
  __shared__ unsigned short Bs[128 * 32];

  int tid = threadIdx.x;
  int lane = tid & 63, wv = tid >> 6;
  int c0 = tid, c1 = tid + 256;
  int am0 = c0 >> 2, ak0 = (c0 & 3) * 8;
  int am1 = c1 >> 2, ak1 = (c1 & 3) * 8;
  const unsigned short* ga0 = H + (size_t)(base + am0) * I_DIM + ak0;
  const unsigned short* ga1 = H + (size_t)(base + am1) * I_DIM + ak1;
  const unsigned short* gb0 = B + (size_t)(n0 + am0) * I_DIM + ak0;
  const unsigned short* gb1 = B + (size_t)(n0 + am1) * I_DIM + ak1;
  unsigned short* lA0 = As + wv * 512; unsigned short* lA1 = As + 2048 + wv * 512;
  unsigned short* lB0 = Bs + wv * 512; unsigned short* lB1 = Bs + 2048 + wv * 512;

  f32x4 acc[4][4] = {};
  int wr = (wv >> 1) * 64, wc = (wv & 1) * 64;
  int l15 = lane & 15, l4 = lane >> 4;

  for (int k0 = 0; k0 < I_DIM; k0 += 32) {
    gload_lds16(ga0 + k0, lA0); gload_lds16(ga1 + k0, lA1);
    gload_lds16(gb0 + k0, lB0); gload_lds16(gb1 + k0, lB1);
    __syncthreads();
    bf16x8 af[4], bf[4];
#pragma unroll
    for (int i = 0; i < 4; ++i) {
      af[i] = *reinterpret_cast<const bf16x8*>(&As[(wr + i * 16 + l15) * 32 + l4 * 8]);
      bf[i] = *reinterpret_cast<const bf16x8*>(&Bs[(wc + i * 16 + l15) * 32 + l4 * 8]);
    }
#pragma unroll
    for (int i = 0; i < 4; ++i)
#pragma unroll
      for (int j = 0; j < 4; ++j)
        acc[i][j] = __builtin_amdgcn_mfma_f32_16x16x32_bf16(af[i], bf[j], acc[i][j], 0, 0, 0);
    __syncthreads();
  }

#pragma unroll
  for (int i = 0; i < 4; ++i) {
    int row = base + wr + i * 16 + l4 * 4;
#pragma unroll
    for (int j = 0; j < 4; ++j) {
      int col = n0 + wc + j * 16 + l15;
#pragma unroll
      for (int r = 0; r < 4; ++r)
        Y[(size_t)(row + r) * D_DIM + col] = f2bf(acc[i][j][r]);
    }
  }
}

// ---------------- 8) combine: out = w0*Y[r0] + w1*Y[r1] + Y[shared] ----------------
__global__ void combine_kernel(const unsigned short* __restrict__ Y, const int* __restrict__ inv,
                               const float* __restrict__ tw, float* __restrict__ out) {
  int g = blockIdx.x * 256 + threadIdx.x;          // T*128 threads, 8 elems each
  int t = g >> 7, d0 = (g & 127) * 8;
  int r0 = inv[2 * t], r1 = inv[2 * t + 1];
  float w0 = tw[2 * t], w1 = tw[2 * t + 1];
  ushort8 y0 = *(const ushort8*)&Y[(size_t)r0 * D_DIM + d0];
  ushort8 y1 = *(const ushort8*)&Y[(size_t)r1 * D_DIM + d0];
  ushort8 ys = *(const ushort8*)&Y[(size_t)(SHARED_BASE + t) * D_DIM + d0];
  float o[8];
#pragma unroll
  for (int j = 0; j < 8; ++j)
    o[j] = w0 * bf2f(y0[j]) + w1 * bf2f(y1[j]) + bf2f(ys[j]);
  float4* op = (float4*)(out + (size_t)t * D_DIM + d0);
  op[0] = make_float4(o[0], o[1], o[2], o[3]);
  op[1] = make_float4(o[4], o[5], o[6], o[7]);
}

// ---------------- launcher ----------------
extern "C" void kernel_launch(void* const* d_in, const int* in_sizes, int n_in,
                              void* d_out, int out_size, void* d_ws, size_t ws_size,
                              hipStream_t stream) {
  const float* x    = (const float*)d_in[0];
  const float* gw   = (const float*)d_in[1];
  const float* upw  = (const float*)d_in[2];
  const float* gpw  = (const float*)d_in[3];
  const float* dww  = (const float*)d_in[4];
  const float* sup  = (const float*)d_in[5];
  const float* sgt  = (const float*)d_in[6];
  const float* sdw  = (const float*)d_in[7];
  float* out = (float*)d_out;

  char* ws = (char*)d_ws;
  unsigned short* xb  = (unsigned short*)(ws + OFF_XB);
  unsigned short* Ut  = (unsigned short*)(ws + OFF_UT);
  unsigned short* Gt  = (unsigned short*)(ws + OFF_GT);
  unsigned short* Dt  = (unsigned short*)(ws + OFF_DT);
  unsigned short* sUt = (unsigned short*)(ws + OFF_SUT);
  unsigned short* sGt = (unsigned short*)(ws + OFF_SGT);
  unsigned short* sDt = (unsigned short*)(ws + OFF_SDT);
  unsigned short* H   = (unsigned short*)(ws + OFF_H);
  unsigned short* Y   = (unsigned short*)(ws + OFF_Y);
  int*   tki   = (int*)(ws + OFF_TOPKI);
  float* tkw   = (float*)(ws + OFF_TOPKW);
  int*   inv   = (int*)(ws + OFF_INV);
  int*   perm  = (int*)(ws + OFF_PERM);
  int*   cnt   = (int*)(ws + OFF_CNT);
  int*   cur   = (int*)(ws + OFF_CUR);
  int*   offs  = (int*)(ws + OFF_OFFS);
  int*   meta  = (int*)(ws + OFF_META);

  hipMemsetAsync(ws + OFF_CNT, 0, 64, stream);  // counts + cursors

  cvt_x_kernel<<<(T_TOK * D_DIM / 8) / 256, 256, 0, stream>>>(x, xb);
  transpose_cvt_kernel<<<dim3(I_DIM / 32, D_DIM / 32, E_EXP), dim3(32, 8), 0, stream>>>(upw, Ut, D_DIM, I_DIM);
  transpose_cvt_kernel<<<dim3(I_DIM / 32, D_DIM / 32, E_EXP), dim3(32, 8), 0, stream>>>(gpw, Gt, D_DIM, I_DIM);
  transpose_cvt_kernel<<<dim3(D_DIM / 32, I_DIM / 32, E_EXP), dim3(32, 8), 0, stream>>>(dww, Dt, I_DIM, D_DIM);
  transpose_cvt_kernel<<<dim3(I_DIM / 32, D_DIM / 32, 1),     dim3(32, 8), 0, stream>>>(sup, sUt, D_DIM, I_DIM);
  transpose_cvt_kernel<<<dim3(I_DIM / 32, D_DIM / 32, 1),     dim3(32, 8), 0, stream>>>(sgt, sGt, D_DIM, I_DIM);
  transpose_cvt_kernel<<<dim3(D_DIM / 32, I_DIM / 32, 1),     dim3(32, 8), 0, stream>>>(sdw, sDt, I_DIM, D_DIM);

  gating_kernel<<<T_TOK / 4, 256, 0, stream>>>(x, gw, tki, tkw, cnt);
  plan_kernel<<<1, 256, 0, stream>>>(cnt, offs, meta, perm);
  scatter_kernel<<<(NPAIR + T_TOK) / 256, 256, 0, stream>>>(tki, offs, cur, perm, inv);

  gemm1_kernel<<<dim3(MAXTILES, I_DIM / 128), 256, 0, stream>>>(xb, Ut, Gt, sUt, sGt, H, meta, perm);
  gemm2_kernel<<<dim3(MAXTILES, D_DIM / 128), 256, 0, stream>>>(H, Dt, sDt, Y, meta);
  combine_kernel<<<(T_TOK * 128) / 256, 256, 0, stream>>>(Y, inv, tkw, out);
}

// Round 2
// 139.765 us; speedup vs baseline: 1.8343x; 1.8343x over previous
//
#include <hip/hip_runtime.h>
#include <hip/hip_bf16.h>
#include <math.h>

// ---------------- problem constants ----------------
#define T_TOK 4096
#define D_DIM 1024
#define I_DIM 512
#define E_EXP 8
#define KSEL 2
#define NPAIR (T_TOK * KSEL)          // 8192
#define ROUTED_CAP 9216               // >= 8192 + 8*127, multiple of 128
#define SHARED_BASE ROUTED_CAP        // 9216
#define RTOT (ROUTED_CAP + T_TOK)     // 13312
#define MAXTILES 104                  // <= 71 routed + 32 shared + slack

typedef __bf16 bf16x8 __attribute__((ext_vector_type(8)));
typedef float f32x4 __attribute__((ext_vector_type(4)));
typedef unsigned short ushort8 __attribute__((ext_vector_type(8)));

// ---------------- scratch layout (bytes) ----------------
constexpr size_t SZ_XB  = (size_t)T_TOK * D_DIM * 2;
constexpr size_t SZ_WT  = (size_t)E_EXP * D_DIM * I_DIM * 2;
constexpr size_t SZ_SWT = (size_t)D_DIM * I_DIM * 2;
constexpr size_t SZ_H   = (size_t)RTOT * I_DIM * 2;
constexpr size_t SZ_Y   = (size_t)RTOT * D_DIM * 2;

constexpr size_t OFF_XB   = 0;
constexpr size_t OFF_UT   = OFF_XB  + SZ_XB;
constexpr size_t OFF_GT   = OFF_UT  + SZ_WT;
constexpr size_t OFF_DT   = OFF_GT  + SZ_WT;
constexpr size_t OFF_SUT  = OFF_DT  + SZ_WT;
constexpr size_t OFF_SGT  = OFF_SUT + SZ_SWT;
constexpr size_t OFF_SDT  = OFF_SGT + SZ_SWT;
constexpr size_t OFF_H    = OFF_SDT + SZ_SWT;
constexpr size_t OFF_Y    = OFF_H   + SZ_H;
constexpr size_t OFF_TOPKI= OFF_Y   + SZ_Y;                 // NPAIR int
constexpr size_t OFF_TOPKW= OFF_TOPKI + (size_t)NPAIR * 4;  // NPAIR float
constexpr size_t OFF_INV  = OFF_TOPKW + (size_t)NPAIR * 4;  // NPAIR int
constexpr size_t OFF_PERM = OFF_INV   + (size_t)NPAIR * 4;  // RTOT int
constexpr size_t OFF_META = OFF_PERM  + (size_t)RTOT * 4;   // MAXTILES int2

// ---------------- helpers ----------------
__device__ __forceinline__ unsigned short f2bf(float f) {
  unsigned int u = __float_as_uint(f);
  unsigned int r = (u + 0x7FFFu + ((u >> 16) & 1u)) >> 16;
  return (unsigned short)r;
}
__device__ __forceinline__ float bf2f(unsigned short s) {
  return __uint_as_float(((unsigned int)s) << 16);
}
__device__ __forceinline__ void gload_lds16(const void* g, void* l) {
  __builtin_amdgcn_global_load_lds(
      (const __attribute__((address_space(1))) void*)g,
      (__attribute__((address_space(3))) void*)l, 16, 0, 0);
}

// ---------------- 1) transpose-convert [R][C] fp32 -> [C][R] bf16 (batched) ----
__global__ void transpose_cvt_kernel(const float* __restrict__ in, unsigned short* __restrict__ out,
                                     int R, int C) {
  __shared__ float t[32][33];
  size_t bo = (size_t)blockIdx.z * R * C;
  in  += bo; out += bo;
  int c0 = blockIdx.x * 32, r0 = blockIdx.y * 32;
  int tx = threadIdx.x, ty = threadIdx.y;          // block (32,8)
#pragma unroll
  for (int i = 0; i < 4; ++i)
    t[ty + 8 * i][tx] = in[(size_t)(r0 + ty + 8 * i) * C + c0 + tx];
  __syncthreads();
#pragma unroll
  for (int i = 0; i < 4; ++i)
    out[(size_t)(c0 + ty + 8 * i) * R + r0 + tx] = f2bf(t[tx][ty + 8 * i]);
}

// ---------------- 2) gating (+ fused x->bf16): logits, top-2, renorm ----------
// One wave per token. No atomics.
__global__ void gating_kernel(const float* __restrict__ x, const float* __restrict__ gw,
                              unsigned short* __restrict__ xb,
                              int* __restrict__ topk_idx, float* __restrict__ topk_w) {
  int lane = threadIdx.x & 63;
  int t = blockIdx.x * 4 + (threadIdx.x >> 6);     // wave per token
  const float4* xr = (const float4*)(x + (size_t)t * D_DIM);
  float4 xv[4];
#pragma unroll
  for (int j = 0; j < 4; ++j) xv[j] = xr[lane + 64 * j];
  // fused fp32 -> bf16 conversion of x (row is fully resident in the wave)
#pragma unroll
  for (int j = 0; j < 4; ++j) {
    ushort4 o;
    o.x = f2bf(xv[j].x); o.y = f2bf(xv[j].y); o.z = f2bf(xv[j].z); o.w = f2bf(xv[j].w);
    *(ushort4*)&xb[(size_t)t * D_DIM + (lane + 64 * j) * 4] = o;
  }
  float acc[E_EXP];
#pragma unroll
  for (int e = 0; e < E_EXP; ++e) {
    const float4* gr = (const float4*)(gw + (size_t)e * D_DIM);
    float a = 0.f;
#pragma unroll
    for (int j = 0; j < 4; ++j) {
      float4 g = gr[lane + 64 * j];
      a += xv[j].x * g.x + xv[j].y * g.y + xv[j].z * g.z + xv[j].w * g.w;
    }
    acc[e] = a;
  }
  // 8 independent butterfly reductions (pipelined shuffles)
#pragma unroll
  for (int off = 32; off; off >>= 1)
#pragma unroll
    for (int e = 0; e < E_EXP; ++e) acc[e] += __shfl_xor(acc[e], off, 64);
  if (lane == 0) {
    int i0 = 0; float m0 = acc[0];
#pragma unroll
    for (int e = 1; e < E_EXP; ++e) if (acc[e] > m0) { m0 = acc[e]; i0 = e; }
    int i1 = -1; float m1 = -1e30f;
#pragma unroll
    for (int e = 0; e < E_EXP; ++e) if (e != i0 && acc[e] > m1) { m1 = acc[e]; i1 = e; }
    float e1 = __expf(m1 - m0);
    float w0 = 1.0f / (1.0f + e1);
    float w1 = e1 / (1.0f + e1);
    topk_idx[2 * t] = i0; topk_idx[2 * t + 1] = i1;
    topk_w[2 * t] = w0;   topk_w[2 * t + 1] = w1;
  }
}

// ---------------- 3) route: counts+offsets+meta+perm+inv, zero atomics --------
// Single block, 256 threads. Ballot-based stable ranking (deterministic).
__global__ __launch_bounds__(256) void route_kernel(
    const int* __restrict__ tidx, int* __restrict__ meta,
    int* __restrict__ perm, int* __restrict__ inv) {
  __shared__ int els[NPAIR];            // 32 KB: cached expert ids
  __shared__ int cnt_iw[128][E_EXP];    // per (chunk,wave) counts
  __shared__ int base_iw[128][E_EXP];   // exclusive prefix within expert
  __shared__ int ebase[E_EXP];
  __shared__ int ecnt[E_EXP];
  int tid = threadIdx.x, lane = tid & 63, wv = tid >> 6;

  // Phase A: load expert ids, per-wave ballot counts
  for (int it = 0; it < NPAIR / 256; ++it) {
    int g = it * 256 + tid;
    int e = tidx[g];
    els[g] = e;
#pragma unroll
    for (int ex = 0; ex < E_EXP; ++ex) {
      unsigned long long m = __ballot(e == ex);
      if (lane == 0) cnt_iw[it * 4 + wv][ex] = __popcll(m);
    }
  }
  __syncthreads();

  // Phase B: per-expert prefix over the 128 (chunk,wave) slots
  if (tid < E_EXP) {
    int s = 0;
    for (int iw = 0; iw < 128; ++iw) { base_iw[iw][tid] = s; s += cnt_iw[iw][tid]; }
    ecnt[tid] = s;
  }
  __syncthreads();

  // segment bases + tile table (single thread; trivial work)
  if (tid == 0) {
    int o = 0, tc = 0;
    int2* m2 = (int2*)meta;
    for (int e = 0; e < E_EXP; ++e) {
      ebase[e] = o;
      int c = ecnt[e];
      int pt = (c + 127) >> 7;
      for (int ti = 0; ti < pt; ++ti) m2[tc++] = make_int2(e, o + ti * 128);
      o += pt * 128;
    }
    for (int ti = 0; ti < T_TOK / 128; ++ti)
      m2[tc++] = make_int2(E_EXP, SHARED_BASE + ti * 128);
    for (; tc < MAXTILES; ++tc) m2[tc] = make_int2(-1, 0);
  }
  __syncthreads();

  // Phase C: stable scatter via ballot rank
  for (int it = 0; it < NPAIR / 256; ++it) {
    int g = it * 256 + tid;
    int e = els[g];
    int rank = 0;
#pragma unroll
    for (int ex = 0; ex < E_EXP; ++ex) {
      unsigned long long m = __ballot(e == ex);
      if (e == ex) rank = __popcll(m & ((1ull << lane) - 1ull));
    }
    int row = ebase[e] + base_iw[it * 4 + wv][e] + rank;
    perm[row] = g >> 1;
    inv[g] = row;
  }
  // pad rows -> token 0 (computed but discarded)
  for (int p = tid; p < E_EXP * 128; p += 256) {
    int e = p >> 7, s = p & 127;
    int c = ecnt[e];
    int padn = (((c + 127) >> 7) << 7) - c;
    if (s < padn) perm[ebase[e] + c + s] = 0;
  }
  // shared expert: identity rows
  for (int t = tid; t < T_TOK; t += 256) perm[SHARED_BASE + t] = t;
}

// ---------------- 4) GEMM1: H = (Xg @ U) * gelu(Xg @ G), bf16 MFMA ----------------
__global__ __launch_bounds__(256, 2) void gemm1_kernel(
    const unsigned short* __restrict__ xb, const unsigned short* __restrict__ Ut,
    const unsigned short* __restrict__ Gt, const unsigned short* __restrict__ sUt,
    const unsigned short* __restrict__ sGt, unsigned short* __restrict__ H,
    const int* __restrict__ meta, const int* __restrict__ perm) {
  int2 m2 = ((const int2*)meta)[blockIdx.x];
  int e = m2.x;
  if (e < 0) return;
  int base = m2.y;
  int n0 = blockIdx.y * 128;
  const unsigned short* BU = (e < E_EXP) ? Ut + (size_t)e * I_DIM * D_DIM : sUt;
  const unsigned short* BG = (e < E_EXP) ? Gt + (size_t)e * I_DIM * D_DIM : sGt;

  __shared__ unsigned short As[128 * 32];
  __shared__ unsigned short BUs[128 * 32];
  __shared__ unsigned short BGs[128 * 32];

  int tid = threadIdx.x;
  int lane = tid & 63, wv = tid >> 6;
  int c0 = tid, c1 = tid + 256;
  int am0 = c0 >> 2, ak0 = (c0 & 3) * 8;
  int am1 = c1 >> 2, ak1 = (c1 & 3) * 8;
  int tok0 = perm[base + am0];
  int tok1 = perm[base + am1];
  const unsigned short* ga0 = xb + (size_t)tok0 * D_DIM + ak0;
  const unsigned short* ga1 = xb + (size_t)tok1 * D_DIM + ak1;
  const unsigned short* gu0 = BU + (size_t)(n0 + am0) * D_DIM + ak0;
  const unsigned short* gu1 = BU + (size_t)(n0 + am1) * D_DIM + ak1;
  const unsigned short* gg0 = BG + (size_t)(n0 + am0) * D_DIM + ak0;
  const unsigned short* gg1 = BG + (size_t)(n0 + am1) * D_DIM + ak1;
  unsigned short* lA0 = As  + wv * 512;  unsigned short* lA1 = As  + 2048 + wv * 512;
  unsigned short* lU0 = BUs + wv * 512;  unsigned short* lU1 = BUs + 2048 + wv * 512;
  unsigned short* lG0 = BGs + wv * 512;  unsigned short* lG1 = BGs + 2048 + wv * 512;

  f32x4 accU[4][4] = {};
  f32x4 accG[4][4] = {};
  int wr = (wv >> 1) * 64, wc = (wv & 1) * 64;
  int l15 = lane & 15, l4 = lane >> 4;

  for (int k0 = 0; k0 < D_DIM; k0 += 32) {
    gload_lds16(ga0 + k0, lA0); gload_lds16(ga1 + k0, lA1);
    gload_lds16(gu0 + k0, lU0); gload_lds16(gu1 + k0, lU1);
    gload_lds16(gg0 + k0, lG0); gload_lds16(gg1 + k0, lG1);
    __syncthreads();
    bf16x8 af[4], uf[4], gf[4];
#pragma unroll
    for (int i = 0; i < 4; ++i) {
      af[i] = *reinterpret_cast<const bf16x8*>(&As [(wr + i * 16 + l15) * 32 + l4 * 8]);
      uf[i] = *reinterpret_cast<const bf16x8*>(&BUs[(wc + i * 16 + l15) * 32 + l4 * 8]);
      gf[i] = *reinterpret_cast<const bf16x8*>(&BGs[(wc + i * 16 + l15) * 32 + l4 * 8]);
    }
#pragma unroll
    for (int i = 0; i < 4; ++i)
#pragma unroll
      for (int j = 0; j < 4; ++j) {
        accU[i][j] = __builtin_amdgcn_mfma_f32_16x16x32_bf16(af[i], uf[j], accU[i][j], 0, 0, 0);
        accG[i][j] = __builtin_amdgcn_mfma_f32_16x16x32_bf16(af[i], gf[j], accG[i][j], 0, 0, 0);
      }
    __syncthreads();
  }

  const float is2 = 0.70710678118654752f;
#pragma unroll
  for (int i = 0; i < 4; ++i) {
    int row = base + wr + i * 16 + l4 * 4;
#pragma unroll
    for (int j = 0; j < 4; ++j) {
      int col = n0 + wc + j * 16 + l15;
#pragma unroll
      for (int r = 0; r < 4; ++r) {
        float u = accU[i][j][r], g = accG[i][j][r];
        float gl = 0.5f * g * (1.0f + erff(g * is2));
        H[(size_t)(row + r) * I_DIM + col] = f2bf(u * gl);
      }
    }
  }
}

// ---------------- 5) GEMM2: Y = H @ Down, bf16 MFMA ----------------
__global__ __launch_bounds__(256, 2) void gemm2_kernel(
    const unsigned short* __restrict__ H, const unsigned short* __restrict__ Dt,
    const unsigned short* __restrict__ sDt, unsigned short* __restrict__ Y,
    const int* __restrict__ meta) {
  int2 m2 = ((const int2*)meta)[blockIdx.x];
  int e = m2.x;
  if (e < 0) return;
  int base = m2.y;
  int n0 = blockIdx.y * 128;
  const unsigned short* B = (e < E_EXP) ? Dt + (size_t)e * D_DIM * I_DIM : sDt;

  __shared__ unsigned short As[128 * 32];
  __shared__ unsigned short Bs[128 * 32];

  int tid = threadIdx.x;
  int lane = tid & 63, wv = tid >> 6;
  int c0 = tid, c1 = tid + 256;
  int am0 = c0 >> 2, ak0 = (c0 & 3) * 8;
  int am1 = c1 >> 2, ak1 = (c1 & 3) * 8;
  const unsigned short* ga0 = H + (size_t)(base + am0) * I_DIM + ak0;
  const unsigned short* ga1 = H + (size_t)(base + am1) * I_DIM + ak1;
  const unsigned short* gb0 = B + (size_t)(n0 + am0) * I_DIM + ak0;
  const unsigned short* gb1 = B + (size_t)(n0 + am1) * I_DIM + ak1;
  unsigned short* lA0 = As + wv * 512; unsigned short* lA1 = As + 2048 + wv * 512;
  unsigned short* lB0 = Bs + wv * 512; unsigned short* lB1 = Bs + 2048 + wv * 512;

  f32x4 acc[4][4] = {};
  int wr = (wv >> 1) * 64, wc = (wv & 1) * 64;
  int l15 = lane & 15, l4 = lane >> 4;

  for (int k0 = 0; k0 < I_DIM; k0 += 32) {
    gload_lds16(ga0 + k0, lA0); gload_lds16(ga1 + k0, lA1);
    gload_lds16(gb0 + k0, lB0); gload_lds16(gb1 + k0, lB1);
    __syncthreads();
    bf16x8 af[4], bf[4];
#pragma unroll
    for (int i = 0; i < 4; ++i) {
      af[i] = *reinterpret_cast<const bf16x8*>(&As[(wr + i * 16 + l15) * 32 + l4 * 8]);
      bf[i] = *reinterpret_cast<const bf16x8*>(&Bs[(wc + i * 16 + l15) * 32 + l4 * 8]);
    }
#pragma unroll
    for (int i = 0; i < 4; ++i)
#pragma unroll
      for (int j = 0; j < 4; ++j)
        acc[i][j] = __builtin_amdgcn_mfma_f32_16x16x32_bf16(af[i], bf[j], acc[i][j], 0, 0, 0);
    __syncthreads();
  }

#pragma unroll
  for (int i = 0; i < 4; ++i) {
    int row = base + wr + i * 16 + l4 * 4;
#pragma unroll
    for (int j = 0; j < 4; ++j) {
      int col = n0 + wc + j * 16 + l15;
#pragma unroll
      for (int r = 0; r < 4; ++r)
        Y[(size_t)(row + r) * D_DIM + col] = f2bf(acc[i][j][r]);
    }
  }
}

// ---------------- 6) combine: out = w0*Y[r0] + w1*Y[r1] + Y[shared] ----------------
__global__ void combine_kernel(const unsigned short* __restrict__ Y, const int* __restrict__ inv,
                               const float* __restrict__ tw, float* __restrict__ out) {
  int g = blockIdx.x * 256 + threadIdx.x;          // T*128 threads, 8 elems each
  int t = g >> 7, d0 = (g & 127) * 8;
  int r0 = inv[2 * t], r1 = inv[2 * t + 1];
  float w0 = tw[2 * t], w1 = tw[2 * t + 1];
  ushort8 y0 = *(const ushort8*)&Y[(size_t)r0 * D_DIM + d0];
  ushort8 y1 = *(const ushort8*)&Y[(size_t)r1 * D_DIM + d0];
  ushort8 ys = *(const ushort8*)&Y[(size_t)(SHARED_BASE + t) * D_DIM + d0];
  float o[8];
#pragma unroll
  for (int j = 0; j < 8; ++j)
    o[j] = w0 * bf2f(y0[j]) + w1 * bf2f(y1[j]) + bf2f(ys[j]);
  float4* op = (float4*)(out + (size_t)t * D_DIM + d0);
  op[0] = make_float4(o[0], o[1], o[2], o[3]);
  op[1] = make_float4(o[4], o[5], o[6], o[7]);
}

// ---------------- launcher ----------------
extern "C" void kernel_launch(void* const* d_in, const int* in_sizes, int n_in,
                              void* d_out, int out_size, void* d_ws, size_t ws_size,
                              hipStream_t stream) {
  const float* x    = (const float*)d_in[0];
  const float* gw   = (const float*)d_in[1];
  const float* upw  = (const float*)d_in[2];
  const float* gpw  = (const float*)d_in[3];
  const float* dww  = (const float*)d_in[4];
  const float* sup  = (const float*)d_in[5];
  const float* sgt  = (const float*)d_in[6];
  const float* sdw  = (const float*)d_in[7];
  float* out = (float*)d_out;

  char* ws = (char*)d_ws;
  unsigned short* xb  = (unsigned short*)(ws + OFF_XB);
  unsigned short* Ut  = (unsigned short*)(ws + OFF_UT);
  unsigned short* Gt  = (unsigned short*)(ws + OFF_GT);
  unsigned short* Dt  = (unsigned short*)(ws + OFF_DT);
  unsigned short* sUt = (unsigned short*)(ws + OFF_SUT);
  unsigned short* sGt = (unsigned short*)(ws + OFF_SGT);
  unsigned short* sDt = (unsigned short*)(ws + OFF_SDT);
  unsigned short* H   = (unsigned short*)(ws + OFF_H);
  unsigned short* Y   = (unsigned short*)(ws + OFF_Y);
  int*   tki   = (int*)(ws + OFF_TOPKI);
  float* tkw   = (float*)(ws + OFF_TOPKW);
  int*   inv   = (int*)(ws + OFF_INV);
  int*   perm  = (int*)(ws + OFF_PERM);
  int*   meta  = (int*)(ws + OFF_META);

  transpose_cvt_kernel<<<dim3(I_DIM / 32, D_DIM / 32, E_EXP), dim3(32, 8), 0, stream>>>(upw, Ut, D_DIM, I_DIM);
  transpose_cvt_kernel<<<dim3(I_DIM / 32, D_DIM / 32, E_EXP), dim3(32, 8), 0, stream>>>(gpw, Gt, D_DIM, I_DIM);
  transpose_cvt_kernel<<<dim3(D_DIM / 32, I_DIM / 32, E_EXP), dim3(32, 8), 0, stream>>>(dww, Dt, I_DIM, D_DIM);
  transpose_cvt_kernel<<<dim3(I_DIM / 32, D_DIM / 32, 1),     dim3(32, 8), 0, stream>>>(sup, sUt, D_DIM, I_DIM);
  transpose_cvt_kernel<<<dim3(I_DIM / 32, D_DIM / 32, 1),     dim3(32, 8), 0, stream>>>(sgt, sGt, D_DIM, I_DIM);
  transpose_cvt_kernel<<<dim3(D_DIM / 32, I_DIM / 32, 1),     dim3(32, 8), 0, stream>>>(sdw, sDt, I_DIM, D_DIM);

  gating_kernel<<<T_TOK / 4, 256, 0, stream>>>(x, gw, xb, tki, tkw);
  route_kernel<<<1, 256, 0, stream>>>(tki, meta, perm, inv);

  gemm1_kernel<<<dim3(MAXTILES, I_DIM / 128), 256, 0, stream>>>(xb, Ut, Gt, sUt, sGt, H, meta, perm);
  gemm2_kernel<<<dim3(MAXTILES, D_DIM / 128), 256, 0, stream>>>(H, Dt, sDt, Y, meta);
  combine_kernel<<<(T_TOK * 128) / 256, 256, 0, stream>>>(Y, inv, tkw, out);
}

// Round 3
// 116.884 us; speedup vs baseline: 2.1933x; 1.1958x over previous
//
#include <hip/hip_runtime.h>
#include <hip/hip_bf16.h>
#include <math.h>

// ---------------- problem constants ----------------
#define T_TOK 4096
#define D_DIM 1024
#define I_DIM 512
#define E_EXP 8
#define KSEL 2
#define NPAIR (T_TOK * KSEL)          // 8192
#define ROUTED_CAP 9216               // >= 8192 + 8*127, multiple of 128
#define SHARED_BASE ROUTED_CAP        // 9216
#define RTOT (ROUTED_CAP + T_TOK)     // 13312
#define MAXTILES 104                  // 72 routed (typ.) + 32 shared
#define GRID_G (MAXTILES * 8)         // 832 = 8 XCDs x 104

typedef __bf16 bf16x8 __attribute__((ext_vector_type(8)));
typedef float f32x4 __attribute__((ext_vector_type(4)));
typedef unsigned short ushort8 __attribute__((ext_vector_type(8)));

// ---------------- scratch layout (bytes) ----------------
constexpr size_t SZ_XB  = (size_t)T_TOK * D_DIM * 2;                 // 8.4 MB
constexpr size_t SZ_UG  = (size_t)E_EXP * 2 * I_DIM * D_DIM * 2;     // 16.8 MB
constexpr size_t SZ_DT  = (size_t)E_EXP * I_DIM * D_DIM * 2;         // 8.4 MB
constexpr size_t SZ_SUG = (size_t)2 * I_DIM * D_DIM * 2;             // 2.1 MB
constexpr size_t SZ_SDT = (size_t)I_DIM * D_DIM * 2;                 // 1.05 MB
constexpr size_t SZ_H   = (size_t)RTOT * I_DIM * 2;                  // 13.6 MB
constexpr size_t SZ_Y   = (size_t)RTOT * D_DIM * 2;                  // 27.3 MB

constexpr size_t OFF_XB   = 0;
constexpr size_t OFF_UG   = OFF_XB  + SZ_XB;
constexpr size_t OFF_DT   = OFF_UG  + SZ_UG;
constexpr size_t OFF_SUG  = OFF_DT  + SZ_DT;
constexpr size_t OFF_SDT  = OFF_SUG + SZ_SUG;
constexpr size_t OFF_H    = OFF_SDT + SZ_SDT;
constexpr size_t OFF_Y    = OFF_H   + SZ_H;
constexpr size_t OFF_TOPKI= OFF_Y   + SZ_Y;                 // NPAIR int
constexpr size_t OFF_TOPKW= OFF_TOPKI + (size_t)NPAIR * 4;  // NPAIR float
constexpr size_t OFF_INV  = OFF_TOPKW + (size_t)NPAIR * 4;  // NPAIR int
constexpr size_t OFF_PERM = OFF_INV   + (size_t)NPAIR * 4;  // RTOT int
constexpr size_t OFF_META = OFF_PERM  + (size_t)RTOT * 4;   // MAXTILES int2

// ---------------- helpers ----------------
__device__ __forceinline__ unsigned short f2bf(float f) {
  unsigned int u = __float_as_uint(f);
  unsigned int r = (u + 0x7FFFu + ((u >> 16) & 1u)) >> 16;
  return (unsigned short)r;
}
__device__ __forceinline__ float bf2f(unsigned short s) {
  return __uint_as_float(((unsigned int)s) << 16);
}
__device__ __forceinline__ void gload_lds16(const void* g, void* l) {
  __builtin_amdgcn_global_load_lds(
      (const __attribute__((address_space(1))) void*)g,
      (__attribute__((address_space(3))) void*)l, 16, 0, 0);
}

// ---------------- 1) merged transpose-convert of ALL weights --------------
// mode 0: U -> UG interleaved rows ((c>>4)<<5)+(c&15)
// mode 1: G -> UG interleaved rows +16
// mode 2: plain transpose (down weights)
__global__ void transpose_cvt_all(
    const float* __restrict__ upw, const float* __restrict__ gpw,
    const float* __restrict__ dww, const float* __restrict__ sup,
    const float* __restrict__ sgt, const float* __restrict__ sdw,
    unsigned short* __restrict__ UG, unsigned short* __restrict__ sUG,
    unsigned short* __restrict__ Dt, unsigned short* __restrict__ sDt) {
  __shared__ float t[32][33];
  int bid = blockIdx.x;
  const float* in; unsigned short* out;
  int R, C, xt, yt, mode;
  if (bid < 4096)       { int e = bid >> 9, s = bid & 511;
    in = upw + (size_t)e * D_DIM * I_DIM; out = UG + (size_t)e * 2 * I_DIM * D_DIM;
    R = D_DIM; C = I_DIM; xt = s & 15; yt = s >> 4; mode = 0; }
  else if (bid < 8192)  { int b = bid - 4096; int e = b >> 9, s = b & 511;
    in = gpw + (size_t)e * D_DIM * I_DIM; out = UG + (size_t)e * 2 * I_DIM * D_DIM;
    R = D_DIM; C = I_DIM; xt = s & 15; yt = s >> 4; mode = 1; }
  else if (bid < 12288) { int b = bid - 8192; int e = b >> 9, s = b & 511;
    in = dww + (size_t)e * I_DIM * D_DIM; out = Dt + (size_t)e * I_DIM * D_DIM;
    R = I_DIM; C = D_DIM; xt = s & 31; yt = s >> 5; mode = 2; }
  else if (bid < 12800) { int s = bid - 12288;
    in = sup; out = sUG; R = D_DIM; C = I_DIM; xt = s & 15; yt = s >> 4; mode = 0; }
  else if (bid < 13312) { int s = bid - 12800;
    in = sgt; out = sUG; R = D_DIM; C = I_DIM; xt = s & 15; yt = s >> 4; mode = 1; }
  else                  { int s = bid - 13312;
    in = sdw; out = sDt; R = I_DIM; C = D_DIM; xt = s & 31; yt = s >> 5; mode = 2; }
  int c0 = xt * 32, r0 = yt * 32;
  int tx = threadIdx.x, ty = threadIdx.y;          // block (32,8)
#pragma unroll
  for (int i = 0; i < 4; ++i)
    t[ty + 8 * i][tx] = in[(size_t)(r0 + ty + 8 * i) * C + c0 + tx];
  __syncthreads();
#pragma unroll
  for (int i = 0; i < 4; ++i) {
    int c = c0 + ty + 8 * i;
    int orow = (mode == 2) ? c : (((c >> 4) << 5) + (c & 15) + (mode == 1 ? 16 : 0));
    out[(size_t)orow * R + r0 + tx] = f2bf(t[tx][ty + 8 * i]);
  }
}

// ---------------- 2) gating (+ fused x->bf16): logits, top-2, renorm ----------
__global__ void gating_kernel(const float* __restrict__ x, const float* __restrict__ gw,
                              unsigned short* __restrict__ xb,
                              int* __restrict__ topk_idx, float* __restrict__ topk_w) {
  int lane = threadIdx.x & 63;
  int t = blockIdx.x * 4 + (threadIdx.x >> 6);     // wave per token
  const float4* xr = (const float4*)(x + (size_t)t * D_DIM);
  float4 xv[4];
#pragma unroll
  for (int j = 0; j < 4; ++j) xv[j] = xr[lane + 64 * j];
#pragma unroll
  for (int j = 0; j < 4; ++j) {
    ushort4 o;
    o.x = f2bf(xv[j].x); o.y = f2bf(xv[j].y); o.z = f2bf(xv[j].z); o.w = f2bf(xv[j].w);
    *(ushort4*)&xb[(size_t)t * D_DIM + (lane + 64 * j) * 4] = o;
  }
  float acc[E_EXP];
#pragma unroll
  for (int e = 0; e < E_EXP; ++e) {
    const float4* gr = (const float4*)(gw + (size_t)e * D_DIM);
    float a = 0.f;
#pragma unroll
    for (int j = 0; j < 4; ++j) {
      float4 g = gr[lane + 64 * j];
      a += xv[j].x * g.x + xv[j].y * g.y + xv[j].z * g.z + xv[j].w * g.w;
    }
    acc[e] = a;
  }
#pragma unroll
  for (int off = 32; off; off >>= 1)
#pragma unroll
    for (int e = 0; e < E_EXP; ++e) acc[e] += __shfl_xor(acc[e], off, 64);
  if (lane == 0) {
    int i0 = 0; float m0 = acc[0];
#pragma unroll
    for (int e = 1; e < E_EXP; ++e) if (acc[e] > m0) { m0 = acc[e]; i0 = e; }
    int i1 = -1; float m1 = -1e30f;
#pragma unroll
    for (int e = 0; e < E_EXP; ++e) if (e != i0 && acc[e] > m1) { m1 = acc[e]; i1 = e; }
    float e1 = __expf(m1 - m0);
    float w0 = 1.0f / (1.0f + e1);
    float w1 = e1 / (1.0f + e1);
    topk_idx[2 * t] = i0; topk_idx[2 * t + 1] = i1;
    topk_w[2 * t] = w0;   topk_w[2 * t + 1] = w1;
  }
}

// ---------------- 3) route: counts+offsets+meta+perm+inv, zero atomics --------
// Single block, 1024 threads. Ballot-based stable ranking (deterministic).
__global__ __launch_bounds__(1024) void route_kernel(
    const int* __restrict__ tidx, int* __restrict__ meta,
    int* __restrict__ perm, int* __restrict__ inv) {
  __shared__ int els[NPAIR];            // 32 KB
  __shared__ int cnt_iw[128][E_EXP];
  __shared__ int base_iw[128][E_EXP];
  __shared__ int ebase[E_EXP];
  __shared__ int ecnt[E_EXP];
  int tid = threadIdx.x, lane = tid & 63, wv = tid >> 6;   // 16 waves

  for (int it = 0; it < NPAIR / 1024; ++it) {              // 8 iters
    int g = it * 1024 + tid;
    int e = tidx[g];
    els[g] = e;
#pragma unroll
    for (int ex = 0; ex < E_EXP; ++ex) {
      unsigned long long m = __ballot(e == ex);
      if (lane == 0) cnt_iw[it * 16 + wv][ex] = __popcll(m);
    }
  }
  __syncthreads();

  if (tid < E_EXP) {
    int s = 0;
    for (int iw = 0; iw < 128; ++iw) { base_iw[iw][tid] = s; s += cnt_iw[iw][tid]; }
    ecnt[tid] = s;
  }
  __syncthreads();

  if (tid == 0) {
    int o = 0, tc = 0;
    int2* m2 = (int2*)meta;
    for (int e = 0; e < E_EXP; ++e) {
      ebase[e] = o;
      int c = ecnt[e];
      int pt = (c + 127) >> 7;
      for (int ti = 0; ti < pt; ++ti) m2[tc++] = make_int2(e, o + ti * 128);
      o += pt * 128;
    }
    for (int ti = 0; ti < T_TOK / 128; ++ti)
      m2[tc++] = make_int2(E_EXP, SHARED_BASE + ti * 128);
    for (; tc < MAXTILES; ++tc) m2[tc] = make_int2(-1, 0);
  }
  __syncthreads();

  for (int it = 0; it < NPAIR / 1024; ++it) {
    int g = it * 1024 + tid;
    int e = els[g];
    int rank = 0;
#pragma unroll
    for (int ex = 0; ex < E_EXP; ++ex) {
      unsigned long long m = __ballot(e == ex);
      if (e == ex) rank = __popcll(m & ((1ull << lane) - 1ull));
    }
    int row = ebase[e] + base_iw[it * 16 + wv][e] + rank;
    perm[row] = g >> 1;
    inv[g] = row;
  }
  // pad rows -> token 0 (computed but discarded)
  {
    int p = tid;                                           // E_EXP*128 == 1024
    int e = p >> 7, s = p & 127;
    int c = ecnt[e];
    int padn = (((c + 127) >> 7) << 7) - c;
    if (s < padn) perm[ebase[e] + c + s] = 0;
  }
  for (int t = tid; t < T_TOK; t += 1024) perm[SHARED_BASE + t] = t;
}

// -------- 4) GEMM1: H = (Xg @ U) * gelu(Xg @ G), interleaved-UG B, bf16 MFMA ---
__global__ __launch_bounds__(256, 3) void gemm1_kernel(
    const unsigned short* __restrict__ xb, const unsigned short* __restrict__ UG,
    const unsigned short* __restrict__ sUG, unsigned short* __restrict__ H,
    const int* __restrict__ meta, const int* __restrict__ perm) {
  int orig = blockIdx.x;
  int wg = (orig & 7) * (GRID_G / 8) + (orig >> 3);  // XCD chunk swizzle (bijective)
  int mt = wg >> 3, nt = wg & 7;
  int2 m2 = ((const int2*)meta)[mt];
  int e = m2.x;
  if (e < 0) return;
  int base = m2.y;
  int n0 = nt * 128;
  const unsigned short* B = (e < E_EXP) ? UG + (size_t)e * 2 * I_DIM * D_DIM : sUG;

  __shared__ unsigned short As[128 * 32];
  __shared__ unsigned short Bs[128 * 32];

  int tid = threadIdx.x, lane = tid & 63, wv = tid >> 6;
  int am0 = tid >> 2, ak0 = (tid & 3) * 8;
  int am1 = am0 + 64;
  int tok0 = perm[base + am0];
  int tok1 = perm[base + am1];
  const unsigned short* ga0 = xb + (size_t)tok0 * D_DIM + ak0;
  const unsigned short* ga1 = xb + (size_t)tok1 * D_DIM + ak0;
  const unsigned short* gb0 = B + (size_t)(n0 + am0) * D_DIM + ak0;
  const unsigned short* gb1 = B + (size_t)(n0 + am1) * D_DIM + ak0;
  unsigned short* lA0 = As + wv * 512; unsigned short* lA1 = As + 2048 + wv * 512;
  unsigned short* lB0 = Bs + wv * 512; unsigned short* lB1 = Bs + 2048 + wv * 512;

  f32x4 acc[4][4] = {};
  int wr = (wv >> 1) * 64, wc = (wv & 1) * 64;
  int l15 = lane & 15, l4 = lane >> 4;

  for (int k0 = 0; k0 < D_DIM; k0 += 32) {
    gload_lds16(ga0 + k0, lA0); gload_lds16(ga1 + k0, lA1);
    gload_lds16(gb0 + k0, lB0); gload_lds16(gb1 + k0, lB1);
    __syncthreads();
    bf16x8 af[4], bf[4];
#pragma unroll
    for (int i = 0; i < 4; ++i) {
      af[i] = *reinterpret_cast<const bf16x8*>(&As[(wr + i * 16 + l15) * 32 + l4 * 8]);
      bf[i] = *reinterpret_cast<const bf16x8*>(&Bs[(wc + i * 16 + l15) * 32 + l4 * 8]);
    }
#pragma unroll
    for (int i = 0; i < 4; ++i)
#pragma unroll
      for (int j = 0; j < 4; ++j)
        acc[i][j] = __builtin_amdgcn_mfma_f32_16x16x32_bf16(af[i], bf[j], acc[i][j], 0, 0, 0);
    __syncthreads();
  }

  // epilogue: frag 2m = U, frag 2m+1 = G for the same logical H column block
  const float is2 = 0.70710678118654752f;
  int hbase = (n0 >> 1) + (wv & 1) * 32;
#pragma unroll
  for (int i = 0; i < 4; ++i) {
    int row = base + wr + i * 16 + l4 * 4;
#pragma unroll
    for (int m = 0; m < 2; ++m) {
      int col = hbase + m * 16 + l15;
#pragma unroll
      for (int r = 0; r < 4; ++r) {
        float u = acc[i][2 * m][r], g = acc[i][2 * m + 1][r];
        float gl = 0.5f * g * (1.0f + erff(g * is2));
        H[(size_t)(row + r) * I_DIM + col] = f2bf(u * gl);
      }
    }
  }
}

// ---------------- 5) GEMM2: Y = H @ Down, bf16 MFMA ----------------
__global__ __launch_bounds__(256, 3) void gemm2_kernel(
    const unsigned short* __restrict__ H, const unsigned short* __restrict__ Dt,
    const unsigned short* __restrict__ sDt, unsigned short* __restrict__ Y,
    const int* __restrict__ meta) {
  int orig = blockIdx.x;
  int wg = (orig & 7) * (GRID_G / 8) + (orig >> 3);
  int mt = wg >> 3, nt = wg & 7;
  int2 m2 = ((const int2*)meta)[mt];
  int e = m2.x;
  if (e < 0) return;
  int base = m2.y;
  int n0 = nt * 128;
  const unsigned short* B = (e < E_EXP) ? Dt + (size_t)e * D_DIM * I_DIM : sDt;

  __shared__ unsigned short As[128 * 32];
  __shared__ unsigned short Bs[128 * 32];

  int tid = threadIdx.x, lane = tid & 63, wv = tid >> 6;
  int am0 = tid >> 2, ak0 = (tid & 3) * 8;
  int am1 = am0 + 64;
  const unsigned short* ga0 = H + (size_t)(base + am0) * I_DIM + ak0;
  const unsigned short* ga1 = H + (size_t)(base + am1) * I_DIM + ak0;
  const unsigned short* gb0 = B + (size_t)(n0 + am0) * I_DIM + ak0;
  const unsigned short* gb1 = B + (size_t)(n0 + am1) * I_DIM + ak0;
  unsigned short* lA0 = As + wv * 512; unsigned short* lA1 = As + 2048 + wv * 512;
  unsigned short* lB0 = Bs + wv * 512; unsigned short* lB1 = Bs + 2048 + wv * 512;

  f32x4 acc[4][4] = {};
  int wr = (wv >> 1) * 64, wc = (wv & 1) * 64;
  int l15 = lane & 15, l4 = lane >> 4;

  for (int k0 = 0; k0 < I_DIM; k0 += 32) {
    gload_lds16(ga0 + k0, lA0); gload_lds16(ga1 + k0, lA1);
    gload_lds16(gb0 + k0, lB0); gload_lds16(gb1 + k0, lB1);
    __syncthreads();
    bf16x8 af[4], bf[4];
#pragma unroll
    for (int i = 0; i < 4; ++i) {
      af[i] = *reinterpret_cast<const bf16x8*>(&As[(wr + i * 16 + l15) * 32 + l4 * 8]);
      bf[i] = *reinterpret_cast<const bf16x8*>(&Bs[(wc + i * 16 + l15) * 32 + l4 * 8]);
    }
#pragma unroll
    for (int i = 0; i < 4; ++i)
#pragma unroll
      for (int j = 0; j < 4; ++j)
        acc[i][j] = __builtin_amdgcn_mfma_f32_16x16x32_bf16(af[i], bf[j], acc[i][j], 0, 0, 0);
    __syncthreads();
  }

#pragma unroll
  for (int i = 0; i < 4; ++i) {
    int row = base + wr + i * 16 + l4 * 4;
#pragma unroll
    for (int j = 0; j < 4; ++j) {
      int col = n0 + wc + j * 16 + l15;
#pragma unroll
      for (int r = 0; r < 4; ++r)
        Y[(size_t)(row + r) * D_DIM + col] = f2bf(acc[i][j][r]);
    }
  }
}

// ---------------- 6) combine: out = w0*Y[r0] + w1*Y[r1] + Y[shared] ----------------
__global__ void combine_kernel(const unsigned short* __restrict__ Y, const int* __restrict__ inv,
                               const float* __restrict__ tw, float* __restrict__ out) {
  int g = blockIdx.x * 256 + threadIdx.x;
  int t = g >> 7, d0 = (g & 127) * 8;
  int r0 = inv[2 * t], r1 = inv[2 * t + 1];
  float w0 = tw[2 * t], w1 = tw[2 * t + 1];
  ushort8 y0 = *(const ushort8*)&Y[(size_t)r0 * D_DIM + d0];
  ushort8 y1 = *(const ushort8*)&Y[(size_t)r1 * D_DIM + d0];
  ushort8 ys = *(const ushort8*)&Y[(size_t)(SHARED_BASE + t) * D_DIM + d0];
  float o[8];
#pragma unroll
  for (int j = 0; j < 8; ++j)
    o[j] = w0 * bf2f(y0[j]) + w1 * bf2f(y1[j]) + bf2f(ys[j]);
  float4* op = (float4*)(out + (size_t)t * D_DIM + d0);
  op[0] = make_float4(o[0], o[1], o[2], o[3]);
  op[1] = make_float4(o[4], o[5], o[6], o[7]);
}

// ---------------- launcher ----------------
extern "C" void kernel_launch(void* const* d_in, const int* in_sizes, int n_in,
                              void* d_out, int out_size, void* d_ws, size_t ws_size,
                              hipStream_t stream) {
  const float* x    = (const float*)d_in[0];
  const float* gw   = (const float*)d_in[1];
  const float* upw  = (const float*)d_in[2];
  const float* gpw  = (const float*)d_in[3];
  const float* dww  = (const float*)d_in[4];
  const float* sup  = (const float*)d_in[5];
  const float* sgt  = (const float*)d_in[6];
  const float* sdw  = (const float*)d_in[7];
  float* out = (float*)d_out;

  char* ws = (char*)d_ws;
  unsigned short* xb  = (unsigned short*)(ws + OFF_XB);
  unsigned short* UG  = (unsigned short*)(ws + OFF_UG);
  unsigned short* Dt  = (unsigned short*)(ws + OFF_DT);
  unsigned short* sUG = (unsigned short*)(ws + OFF_SUG);
  unsigned short* sDt = (unsigned short*)(ws + OFF_SDT);
  unsigned short* H   = (unsigned short*)(ws + OFF_H);
  unsigned short* Y   = (unsigned short*)(ws + OFF_Y);
  int*   tki   = (int*)(ws + OFF_TOPKI);
  float* tkw   = (float*)(ws + OFF_TOPKW);
  int*   inv   = (int*)(ws + OFF_INV);
  int*   perm  = (int*)(ws + OFF_PERM);
  int*   meta  = (int*)(ws + OFF_META);

  transpose_cvt_all<<<13824, dim3(32, 8), 0, stream>>>(upw, gpw, dww, sup, sgt, sdw,
                                                       UG, sUG, Dt, sDt);
  gating_kernel<<<T_TOK / 4, 256, 0, stream>>>(x, gw, xb, tki, tkw);
  route_kernel<<<1, 1024, 0, stream>>>(tki, meta, perm, inv);

  gemm1_kernel<<<GRID_G, 256, 0, stream>>>(xb, UG, sUG, H, meta, perm);
  gemm2_kernel<<<GRID_G, 256, 0, stream>>>(H, Dt, sDt, Y, meta);
  combine_kernel<<<(T_TOK * 128) / 256, 256, 0, stream>>>(Y, inv, tkw, out);
}

// Round 4
// 113.009 us; speedup vs baseline: 2.2686x; 1.0343x over previous
//
#include <hip/hip_runtime.h>
#include <hip/hip_bf16.h>
#include <math.h>

// ---------------- problem constants ----------------
#define T_TOK 4096
#define D_DIM 1024
#define I_DIM 512
#define E_EXP 8
#define KSEL 2
#define NPAIR (T_TOK * KSEL)          // 8192
#define ROUTED_CAP 9216               // >= 8192 + 8*127, multiple of 128
#define SHARED_BASE ROUTED_CAP        // 9216
#define RTOT (ROUTED_CAP + T_TOK)     // 13312
#define MAXTILES 104                  // 72 routed (typ.) + 32 shared
#define GRID_G (MAXTILES * 8)         // 832 = 8 XCDs x 104

typedef __bf16 bf16x8 __attribute__((ext_vector_type(8)));
typedef float f32x4 __attribute__((ext_vector_type(4)));
typedef unsigned short ushort8 __attribute__((ext_vector_type(8)));

// ---------------- scratch layout (bytes) ----------------
constexpr size_t SZ_XB  = (size_t)T_TOK * D_DIM * 2;                 // 8.4 MB
constexpr size_t SZ_UG  = (size_t)E_EXP * 2 * I_DIM * D_DIM * 2;     // 16.8 MB
constexpr size_t SZ_DT  = (size_t)E_EXP * I_DIM * D_DIM * 2;         // 8.4 MB
constexpr size_t SZ_SUG = (size_t)2 * I_DIM * D_DIM * 2;             // 2.1 MB
constexpr size_t SZ_SDT = (size_t)I_DIM * D_DIM * 2;                 // 1.05 MB
constexpr size_t SZ_H   = (size_t)RTOT * I_DIM * 2;                  // 13.6 MB
constexpr size_t SZ_Y   = (size_t)RTOT * D_DIM * 2;                  // 27.3 MB

constexpr size_t OFF_XB   = 0;
constexpr size_t OFF_UG   = OFF_XB  + SZ_XB;
constexpr size_t OFF_DT   = OFF_UG  + SZ_UG;
constexpr size_t OFF_SUG  = OFF_DT  + SZ_DT;
constexpr size_t OFF_SDT  = OFF_SUG + SZ_SUG;
constexpr size_t OFF_H    = OFF_SDT + SZ_SDT;
constexpr size_t OFF_Y    = OFF_H   + SZ_H;
constexpr size_t OFF_TOPKI= OFF_Y   + SZ_Y;                 // NPAIR int
constexpr size_t OFF_TOPKW= OFF_TOPKI + (size_t)NPAIR * 4;  // NPAIR float
constexpr size_t OFF_INV  = OFF_TOPKW + (size_t)NPAIR * 4;  // NPAIR int
constexpr size_t OFF_PERM = OFF_INV   + (size_t)NPAIR * 4;  // RTOT int
constexpr size_t OFF_META = OFF_PERM  + (size_t)RTOT * 4;   // MAXTILES int2

// ---------------- helpers ----------------
__device__ __forceinline__ unsigned short f2bf(float f) {
  unsigned int u = __float_as_uint(f);
  unsigned int r = (u + 0x7FFFu + ((u >> 16) & 1u)) >> 16;
  return (unsigned short)r;
}
__device__ __forceinline__ float bf2f(unsigned short s) {
  return __uint_as_float(((unsigned int)s) << 16);
}
__device__ __forceinline__ void gload_lds16(const void* g, void* l) {
  __builtin_amdgcn_global_load_lds(
      (const __attribute__((address_space(1))) void*)g,
      (__attribute__((address_space(3))) void*)l, 16, 0, 0);
}

// ---------------- 1) merged transpose-convert of ALL weights --------------
__global__ void transpose_cvt_all(
    const float* __restrict__ upw, const float* __restrict__ gpw,
    const float* __restrict__ dww, const float* __restrict__ sup,
    const float* __restrict__ sgt, const float* __restrict__ sdw,
    unsigned short* __restrict__ UG, unsigned short* __restrict__ sUG,
    unsigned short* __restrict__ Dt, unsigned short* __restrict__ sDt) {
  __shared__ float t[32][33];
  int bid = blockIdx.x;
  const float* in; unsigned short* out;
  int R, C, xt, yt, mode;
  if (bid < 4096)       { int e = bid >> 9, s = bid & 511;
    in = upw + (size_t)e * D_DIM * I_DIM; out = UG + (size_t)e * 2 * I_DIM * D_DIM;
    R = D_DIM; C = I_DIM; xt = s & 15; yt = s >> 4; mode = 0; }
  else if (bid < 8192)  { int b = bid - 4096; int e = b >> 9, s = b & 511;
    in = gpw + (size_t)e * D_DIM * I_DIM; out = UG + (size_t)e * 2 * I_DIM * D_DIM;
    R = D_DIM; C = I_DIM; xt = s & 15; yt = s >> 4; mode = 1; }
  else if (bid < 12288) { int b = bid - 8192; int e = b >> 9, s = b & 511;
    in = dww + (size_t)e * I_DIM * D_DIM; out = Dt + (size_t)e * I_DIM * D_DIM;
    R = I_DIM; C = D_DIM; xt = s & 31; yt = s >> 5; mode = 2; }
  else if (bid < 12800) { int s = bid - 12288;
    in = sup; out = sUG; R = D_DIM; C = I_DIM; xt = s & 15; yt = s >> 4; mode = 0; }
  else if (bid < 13312) { int s = bid - 12800;
    in = sgt; out = sUG; R = D_DIM; C = I_DIM; xt = s & 15; yt = s >> 4; mode = 1; }
  else                  { int s = bid - 13312;
    in = sdw; out = sDt; R = I_DIM; C = D_DIM; xt = s & 31; yt = s >> 5; mode = 2; }
  int c0 = xt * 32, r0 = yt * 32;
  int tx = threadIdx.x, ty = threadIdx.y;          // block (32,8)
#pragma unroll
  for (int i = 0; i < 4; ++i)
    t[ty + 8 * i][tx] = in[(size_t)(r0 + ty + 8 * i) * C + c0 + tx];
  __syncthreads();
#pragma unroll
  for (int i = 0; i < 4; ++i) {
    int c = c0 + ty + 8 * i;
    int orow = (mode == 2) ? c : (((c >> 4) << 5) + (c & 15) + (mode == 1 ? 16 : 0));
    out[(size_t)orow * R + r0 + tx] = f2bf(t[tx][ty + 8 * i]);
  }
}

// ---------------- 2) gating (+ fused x->bf16): logits, top-2, renorm ----------
__global__ void gating_kernel(const float* __restrict__ x, const float* __restrict__ gw,
                              unsigned short* __restrict__ xb,
                              int* __restrict__ topk_idx, float* __restrict__ topk_w) {
  int lane = threadIdx.x & 63;
  int t = blockIdx.x * 4 + (threadIdx.x >> 6);     // wave per token
  const float4* xr = (const float4*)(x + (size_t)t * D_DIM);
  float4 xv[4];
#pragma unroll
  for (int j = 0; j < 4; ++j) xv[j] = xr[lane + 64 * j];
#pragma unroll
  for (int j = 0; j < 4; ++j) {
    ushort4 o;
    o.x = f2bf(xv[j].x); o.y = f2bf(xv[j].y); o.z = f2bf(xv[j].z); o.w = f2bf(xv[j].w);
    *(ushort4*)&xb[(size_t)t * D_DIM + (lane + 64 * j) * 4] = o;
  }
  float acc[E_EXP];
#pragma unroll
  for (int e = 0; e < E_EXP; ++e) {
    const float4* gr = (const float4*)(gw + (size_t)e * D_DIM);
    float a = 0.f;
#pragma unroll
    for (int j = 0; j < 4; ++j) {
      float4 g = gr[lane + 64 * j];
      a += xv[j].x * g.x + xv[j].y * g.y + xv[j].z * g.z + xv[j].w * g.w;
    }
    acc[e] = a;
  }
#pragma unroll
  for (int off = 32; off; off >>= 1)
#pragma unroll
    for (int e = 0; e < E_EXP; ++e) acc[e] += __shfl_xor(acc[e], off, 64);
  if (lane == 0) {
    int i0 = 0; float m0 = acc[0];
#pragma unroll
    for (int e = 1; e < E_EXP; ++e) if (acc[e] > m0) { m0 = acc[e]; i0 = e; }
    int i1 = -1; float m1 = -1e30f;
#pragma unroll
    for (int e = 0; e < E_EXP; ++e) if (e != i0 && acc[e] > m1) { m1 = acc[e]; i1 = e; }
    float e1 = __expf(m1 - m0);
    float w0 = 1.0f / (1.0f + e1);
    float w1 = e1 / (1.0f + e1);
    topk_idx[2 * t] = i0; topk_idx[2 * t + 1] = i1;
    topk_w[2 * t] = w0;   topk_w[2 * t + 1] = w1;
  }
}

// ---------------- 3) route: counts+offsets+meta+perm+inv, zero atomics --------
__global__ __launch_bounds__(1024) void route_kernel(
    const int* __restrict__ tidx, int* __restrict__ meta,
    int* __restrict__ perm, int* __restrict__ inv) {
  __shared__ int els[NPAIR];            // 32 KB
  __shared__ int cnt_iw[128][E_EXP];
  __shared__ int base_iw[128][E_EXP];
  __shared__ int ebase[E_EXP];
  __shared__ int ecnt[E_EXP];
  int tid = threadIdx.x, lane = tid & 63, wv = tid >> 6;   // 16 waves

  for (int it = 0; it < NPAIR / 1024; ++it) {              // 8 iters
    int g = it * 1024 + tid;
    int e = tidx[g];
    els[g] = e;
#pragma unroll
    for (int ex = 0; ex < E_EXP; ++ex) {
      unsigned long long m = __ballot(e == ex);
      if (lane == 0) cnt_iw[it * 16 + wv][ex] = __popcll(m);
    }
  }
  __syncthreads();

  if (tid < E_EXP) {
    int s = 0;
    for (int iw = 0; iw < 128; ++iw) { base_iw[iw][tid] = s; s += cnt_iw[iw][tid]; }
    ecnt[tid] = s;
  }
  __syncthreads();

  if (tid == 0) {
    int o = 0, tc = 0;
    int2* m2 = (int2*)meta;
    for (int e = 0; e < E_EXP; ++e) {
      ebase[e] = o;
      int c = ecnt[e];
      int pt = (c + 127) >> 7;
      for (int ti = 0; ti < pt; ++ti) m2[tc++] = make_int2(e, o + ti * 128);
      o += pt * 128;
    }
    for (int ti = 0; ti < T_TOK / 128; ++ti)
      m2[tc++] = make_int2(E_EXP, SHARED_BASE + ti * 128);
    for (; tc < MAXTILES; ++tc) m2[tc] = make_int2(-1, 0);
  }
  __syncthreads();

  for (int it = 0; it < NPAIR / 1024; ++it) {
    int g = it * 1024 + tid;
    int e = els[g];
    int rank = 0;
#pragma unroll
    for (int ex = 0; ex < E_EXP; ++ex) {
      unsigned long long m = __ballot(e == ex);
      if (e == ex) rank = __popcll(m & ((1ull << lane) - 1ull));
    }
    int row = ebase[e] + base_iw[it * 16 + wv][e] + rank;
    perm[row] = g >> 1;
    inv[g] = row;
  }
  {
    int p = tid;                                           // E_EXP*128 == 1024
    int e = p >> 7, s = p & 127;
    int c = ecnt[e];
    int padn = (((c + 127) >> 7) << 7) - c;
    if (s < padn) perm[ebase[e] + c + s] = 0;
  }
  for (int t = tid; t < T_TOK; t += 1024) perm[SHARED_BASE + t] = t;
}

// -------- 4) GEMM1: BK=64, XOR-swizzled LDS (linear dest, pre-swizzled src) ---
__global__ __launch_bounds__(256, 3) void gemm1_kernel(
    const unsigned short* __restrict__ xb, const unsigned short* __restrict__ UG,
    const unsigned short* __restrict__ sUG, unsigned short* __restrict__ H,
    const int* __restrict__ meta, const int* __restrict__ perm) {
  int orig = blockIdx.x;
  int wg = (orig & 7) * (GRID_G / 8) + (orig >> 3);  // XCD chunk swizzle (bijective)
  int mt = wg >> 3, nt = wg & 7;
  int2 m2 = ((const int2*)meta)[mt];
  int e = m2.x;
  if (e < 0) return;
  int base = m2.y;
  int n0 = nt * 128;
  const unsigned short* B = (e < E_EXP) ? UG + (size_t)e * 2 * I_DIM * D_DIM : sUG;

  __shared__ unsigned short As[128 * 64];   // 16 KB, row stride 64 elem (128 B)
  __shared__ unsigned short Bs[128 * 64];

  int tid = threadIdx.x, lane = tid & 63, wv = tid >> 6;
  // staging: 1024 16B-chunks per array, 4 per thread. chunk c: row=c>>3, q=c&7.
  // source k-offset swizzled by row (qs = q ^ (row&7)); LDS dest stays linear.
  const unsigned short *gA[4], *gB[4];
  unsigned short *lA[4], *lB[4];
#pragma unroll
  for (int j = 0; j < 4; ++j) {
    int c = j * 256 + tid;
    int row = c >> 3, q = c & 7, qs = q ^ (row & 7);
    int tok = perm[base + row];
    gA[j] = xb + (size_t)tok * D_DIM + qs * 8;
    gB[j] = B + (size_t)(n0 + row) * D_DIM + qs * 8;
    int dbase = (j * 256 + wv * 64) * 8;             // wave-uniform 16B-linear dest
    lA[j] = As + dbase; lB[j] = Bs + dbase;
  }

  f32x4 acc[4][4] = {};
  int wr = (wv >> 1) * 64, wc = (wv & 1) * 64;
  int l15 = lane & 15, l4 = lane >> 4;
  int sx = l15 & 7;                                  // read-side XOR term

  for (int k0 = 0; k0 < D_DIM; k0 += 64) {
#pragma unroll
    for (int j = 0; j < 4; ++j) { gload_lds16(gA[j] + k0, lA[j]); gload_lds16(gB[j] + k0, lB[j]); }
    __syncthreads();
#pragma unroll
    for (int kh = 0; kh < 2; ++kh) {
      bf16x8 af[4], bf[4];
      int kb = kh * 4 + l4;
#pragma unroll
      for (int i = 0; i < 4; ++i) {
        af[i] = *reinterpret_cast<const bf16x8*>(&As[(wr + i * 16 + l15) * 64 + (kb ^ sx) * 8]);
        bf[i] = *reinterpret_cast<const bf16x8*>(&Bs[(wc + i * 16 + l15) * 64 + (kb ^ sx) * 8]);
      }
#pragma unroll
      for (int i = 0; i < 4; ++i)
#pragma unroll
        for (int j = 0; j < 4; ++j)
          acc[i][j] = __builtin_amdgcn_mfma_f32_16x16x32_bf16(af[i], bf[j], acc[i][j], 0, 0, 0);
    }
    __syncthreads();
  }

  // epilogue: frag 2m = U, frag 2m+1 = G for the same logical H column block
  const float is2 = 0.70710678118654752f;
  int hbase = (n0 >> 1) + (wv & 1) * 32;
#pragma unroll
  for (int i = 0; i < 4; ++i) {
    int row = base + wr + i * 16 + l4 * 4;
#pragma unroll
    for (int m = 0; m < 2; ++m) {
      int col = hbase + m * 16 + l15;
#pragma unroll
      for (int r = 0; r < 4; ++r) {
        float u = acc[i][2 * m][r], g = acc[i][2 * m + 1][r];
        float gl = 0.5f * g * (1.0f + erff(g * is2));
        H[(size_t)(row + r) * I_DIM + col] = f2bf(u * gl);
      }
    }
  }
}

// ---------------- 5) GEMM2: Y = H @ Down, BK=64 swizzled, bf16 MFMA -----------
__global__ __launch_bounds__(256, 3) void gemm2_kernel(
    const unsigned short* __restrict__ H, const unsigned short* __restrict__ Dt,
    const unsigned short* __restrict__ sDt, unsigned short* __restrict__ Y,
    const int* __restrict__ meta) {
  int orig = blockIdx.x;
  int wg = (orig & 7) * (GRID_G / 8) + (orig >> 3);
  int mt = wg >> 3, nt = wg & 7;
  int2 m2 = ((const int2*)meta)[mt];
  int e = m2.x;
  if (e < 0) return;
  int base = m2.y;
  int n0 = nt * 128;
  const unsigned short* B = (e < E_EXP) ? Dt + (size_t)e * D_DIM * I_DIM : sDt;

  __shared__ unsigned short As[128 * 64];
  __shared__ unsigned short Bs[128 * 64];

  int tid = threadIdx.x, lane = tid & 63, wv = tid >> 6;
  const unsigned short *gA[4], *gB[4];
  unsigned short *lA[4], *lB[4];
#pragma unroll
  for (int j = 0; j < 4; ++j) {
    int c = j * 256 + tid;
    int row = c >> 3, q = c & 7, qs = q ^ (row & 7);
    gA[j] = H + (size_t)(base + row) * I_DIM + qs * 8;
    gB[j] = B + (size_t)(n0 + row) * I_DIM + qs * 8;
    int dbase = (j * 256 + wv * 64) * 8;
    lA[j] = As + dbase; lB[j] = Bs + dbase;
  }

  f32x4 acc[4][4] = {};
  int wr = (wv >> 1) * 64, wc = (wv & 1) * 64;
  int l15 = lane & 15, l4 = lane >> 4;
  int sx = l15 & 7;

  for (int k0 = 0; k0 < I_DIM; k0 += 64) {
#pragma unroll
    for (int j = 0; j < 4; ++j) { gload_lds16(gA[j] + k0, lA[j]); gload_lds16(gB[j] + k0, lB[j]); }
    __syncthreads();
#pragma unroll
    for (int kh = 0; kh < 2; ++kh) {
      bf16x8 af[4], bf[4];
      int kb = kh * 4 + l4;
#pragma unroll
      for (int i = 0; i < 4; ++i) {
        af[i] = *reinterpret_cast<const bf16x8*>(&As[(wr + i * 16 + l15) * 64 + (kb ^ sx) * 8]);
        bf[i] = *reinterpret_cast<const bf16x8*>(&Bs[(wc + i * 16 + l15) * 64 + (kb ^ sx) * 8]);
      }
#pragma unroll
      for (int i = 0; i < 4; ++i)
#pragma unroll
        for (int j = 0; j < 4; ++j)
          acc[i][j] = __builtin_amdgcn_mfma_f32_16x16x32_bf16(af[i], bf[j], acc[i][j], 0, 0, 0);
    }
    __syncthreads();
  }

#pragma unroll
  for (int i = 0; i < 4; ++i) {
    int row = base + wr + i * 16 + l4 * 4;
#pragma unroll
    for (int j = 0; j < 4; ++j) {
      int col = n0 + wc + j * 16 + l15;
#pragma unroll
      for (int r = 0; r < 4; ++r)
        Y[(size_t)(row + r) * D_DIM + col] = f2bf(acc[i][j][r]);
    }
  }
}

// ---------------- 6) combine: out = w0*Y[r0] + w1*Y[r1] + Y[shared] ----------------
__global__ void combine_kernel(const unsigned short* __restrict__ Y, const int* __restrict__ inv,
                               const float* __restrict__ tw, float* __restrict__ out) {
  int g = blockIdx.x * 256 + threadIdx.x;
  int t = g >> 7, d0 = (g & 127) * 8;
  int r0 = inv[2 * t], r1 = inv[2 * t + 1];
  float w0 = tw[2 * t], w1 = tw[2 * t + 1];
  ushort8 y0 = *(const ushort8*)&Y[(size_t)r0 * D_DIM + d0];
  ushort8 y1 = *(const ushort8*)&Y[(size_t)r1 * D_DIM + d0];
  ushort8 ys = *(const ushort8*)&Y[(size_t)(SHARED_BASE + t) * D_DIM + d0];
  float o[8];
#pragma unroll
  for (int j = 0; j < 8; ++j)
    o[j] = w0 * bf2f(y0[j]) + w1 * bf2f(y1[j]) + bf2f(ys[j]);
  float4* op = (float4*)(out + (size_t)t * D_DIM + d0);
  op[0] = make_float4(o[0], o[1], o[2], o[3]);
  op[1] = make_float4(o[4], o[5], o[6], o[7]);
}

// ---------------- launcher ----------------
extern "C" void kernel_launch(void* const* d_in, const int* in_sizes, int n_in,
                              void* d_out, int out_size, void* d_ws, size_t ws_size,
                              hipStream_t stream) {
  const float* x    = (const float*)d_in[0];
  const float* gw   = (const float*)d_in[1];
  const float* upw  = (const float*)d_in[2];
  const float* gpw  = (const float*)d_in[3];
  const float* dww  = (const float*)d_in[4];
  const float* sup  = (const float*)d_in[5];
  const float* sgt  = (const float*)d_in[6];
  const float* sdw  = (const float*)d_in[7];
  float* out = (float*)d_out;

  char* ws = (char*)d_ws;
  unsigned short* xb  = (unsigned short*)(ws + OFF_XB);
  unsigned short* UG  = (unsigned short*)(ws + OFF_UG);
  unsigned short* Dt  = (unsigned short*)(ws + OFF_DT);
  unsigned short* sUG = (unsigned short*)(ws + OFF_SUG);
  unsigned short* sDt = (unsigned short*)(ws + OFF_SDT);
  unsigned short* H   = (unsigned short*)(ws + OFF_H);
  unsigned short* Y   = (unsigned short*)(ws + OFF_Y);
  int*   tki   = (int*)(ws + OFF_TOPKI);
  float* tkw   = (float*)(ws + OFF_TOPKW);
  int*   inv   = (int*)(ws + OFF_INV);
  int*   perm  = (int*)(ws + OFF_PERM);
  int*   meta  = (int*)(ws + OFF_META);

  transpose_cvt_all<<<13824, dim3(32, 8), 0, stream>>>(upw, gpw, dww, sup, sgt, sdw,
                                                       UG, sUG, Dt, sDt);
  gating_kernel<<<T_TOK / 4, 256, 0, stream>>>(x, gw, xb, tki, tkw);
  route_kernel<<<1, 1024, 0, stream>>>(tki, meta, perm, inv);

  gemm1_kernel<<<GRID_G, 256, 0, stream>>>(xb, UG, sUG, H, meta, perm);
  gemm2_kernel<<<GRID_G, 256, 0, stream>>>(H, Dt, sDt, Y, meta);
  combine_kernel<<<(T_TOK * 128) / 256, 256, 0, stream>>>(Y, inv, tkw, out);
}

// Round 5
// 110.522 us; speedup vs baseline: 2.3196x; 1.0225x over previous
//
#include <hip/hip_runtime.h>
#include <hip/hip_bf16.h>
#include <math.h>

// ---------------- problem constants ----------------
#define T_TOK 4096
#define D_DIM 1024
#define I_DIM 512
#define E_EXP 8
#define KSEL 2
#define NPAIR (T_TOK * KSEL)          // 8192
#define ROUTED_CAP 9216               // >= 8192 + 8*127, multiple of 128
#define SHARED_BASE ROUTED_CAP        // 9216
#define RTOT (ROUTED_CAP + T_TOK)     // 13312
#define MAXTILES 104                  // 72 routed (typ.) + 32 shared
#define GRID_G (MAXTILES * 8)         // 832 = 8 XCDs x 104

typedef __bf16 bf16x8 __attribute__((ext_vector_type(8)));
typedef float f32x4 __attribute__((ext_vector_type(4)));
typedef unsigned short ushort8 __attribute__((ext_vector_type(8)));

// ---------------- scratch layout (bytes) ----------------
constexpr size_t SZ_XB  = (size_t)T_TOK * D_DIM * 2;                 // 8.4 MB
constexpr size_t SZ_UG  = (size_t)E_EXP * 2 * I_DIM * D_DIM * 2;     // 16.8 MB
constexpr size_t SZ_DT  = (size_t)E_EXP * I_DIM * D_DIM * 2;         // 8.4 MB
constexpr size_t SZ_SUG = (size_t)2 * I_DIM * D_DIM * 2;             // 2.1 MB
constexpr size_t SZ_SDT = (size_t)I_DIM * D_DIM * 2;                 // 1.05 MB
constexpr size_t SZ_H   = (size_t)RTOT * I_DIM * 2;                  // 13.6 MB
constexpr size_t SZ_Y   = (size_t)RTOT * D_DIM * 2;                  // 27.3 MB

constexpr size_t OFF_XB   = 0;
constexpr size_t OFF_UG   = OFF_XB  + SZ_XB;
constexpr size_t OFF_DT   = OFF_UG  + SZ_UG;
constexpr size_t OFF_SUG  = OFF_DT  + SZ_DT;
constexpr size_t OFF_SDT  = OFF_SUG + SZ_SUG;
constexpr size_t OFF_H    = OFF_SDT + SZ_SDT;
constexpr size_t OFF_Y    = OFF_H   + SZ_H;
constexpr size_t OFF_TOPKI= OFF_Y   + SZ_Y;                 // NPAIR int
constexpr size_t OFF_TOPKW= OFF_TOPKI + (size_t)NPAIR * 4;  // NPAIR float
constexpr size_t OFF_INV  = OFF_TOPKW + (size_t)NPAIR * 4;  // NPAIR int
constexpr size_t OFF_PERM = OFF_INV   + (size_t)NPAIR * 4;  // RTOT int
constexpr size_t OFF_META = OFF_PERM  + (size_t)RTOT * 4;   // MAXTILES int2

// ---------------- helpers ----------------
__device__ __forceinline__ unsigned short f2bf(float f) {
  unsigned int u = __float_as_uint(f);
  unsigned int r = (u + 0x7FFFu + ((u >> 16) & 1u)) >> 16;
  return (unsigned short)r;
}
__device__ __forceinline__ float bf2f(unsigned short s) {
  return __uint_as_float(((unsigned int)s) << 16);
}
__device__ __forceinline__ void gload_lds16(const void* g, void* l) {
  __builtin_amdgcn_global_load_lds(
      (const __attribute__((address_space(1))) void*)g,
      (__attribute__((address_space(3))) void*)l, 16, 0, 0);
}

// ---------------- 1) merged transpose-convert of ALL weights --------------
__global__ void transpose_cvt_all(
    const float* __restrict__ upw, const float* __restrict__ gpw,
    const float* __restrict__ dww, const float* __restrict__ sup,
    const float* __restrict__ sgt, const float* __restrict__ sdw,
    unsigned short* __restrict__ UG, unsigned short* __restrict__ sUG,
    unsigned short* __restrict__ Dt, unsigned short* __restrict__ sDt) {
  __shared__ float t[32][33];
  int bid = blockIdx.x;
  const float* in; unsigned short* out;
  int R, C, xt, yt, mode;
  if (bid < 4096)       { int e = bid >> 9, s = bid & 511;
    in = upw + (size_t)e * D_DIM * I_DIM; out = UG + (size_t)e * 2 * I_DIM * D_DIM;
    R = D_DIM; C = I_DIM; xt = s & 15; yt = s >> 4; mode = 0; }
  else if (bid < 8192)  { int b = bid - 4096; int e = b >> 9, s = b & 511;
    in = gpw + (size_t)e * D_DIM * I_DIM; out = UG + (size_t)e * 2 * I_DIM * D_DIM;
    R = D_DIM; C = I_DIM; xt = s & 15; yt = s >> 4; mode = 1; }
  else if (bid < 12288) { int b = bid - 8192; int e = b >> 9, s = b & 511;
    in = dww + (size_t)e * I_DIM * D_DIM; out = Dt + (size_t)e * I_DIM * D_DIM;
    R = I_DIM; C = D_DIM; xt = s & 31; yt = s >> 5; mode = 2; }
  else if (bid < 12800) { int s = bid - 12288;
    in = sup; out = sUG; R = D_DIM; C = I_DIM; xt = s & 15; yt = s >> 4; mode = 0; }
  else if (bid < 13312) { int s = bid - 12800;
    in = sgt; out = sUG; R = D_DIM; C = I_DIM; xt = s & 15; yt = s >> 4; mode = 1; }
  else                  { int s = bid - 13312;
    in = sdw; out = sDt; R = I_DIM; C = D_DIM; xt = s & 31; yt = s >> 5; mode = 2; }
  int c0 = xt * 32, r0 = yt * 32;
  int tx = threadIdx.x, ty = threadIdx.y;          // block (32,8)
#pragma unroll
  for (int i = 0; i < 4; ++i)
    t[ty + 8 * i][tx] = in[(size_t)(r0 + ty + 8 * i) * C + c0 + tx];
  __syncthreads();
#pragma unroll
  for (int i = 0; i < 4; ++i) {
    int c = c0 + ty + 8 * i;
    int orow = (mode == 2) ? c : (((c >> 4) << 5) + (c & 15) + (mode == 1 ? 16 : 0));
    out[(size_t)orow * R + r0 + tx] = f2bf(t[tx][ty + 8 * i]);
  }
}

// ---------------- 2) gating (+ fused x->bf16): logits, top-2, renorm ----------
__global__ void gating_kernel(const float* __restrict__ x, const float* __restrict__ gw,
                              unsigned short* __restrict__ xb,
                              int* __restrict__ topk_idx, float* __restrict__ topk_w) {
  int lane = threadIdx.x & 63;
  int t = blockIdx.x * 4 + (threadIdx.x >> 6);     // wave per token
  const float4* xr = (const float4*)(x + (size_t)t * D_DIM);
  float4 xv[4];
#pragma unroll
  for (int j = 0; j < 4; ++j) xv[j] = xr[lane + 64 * j];
#pragma unroll
  for (int j = 0; j < 4; ++j) {
    ushort4 o;
    o.x = f2bf(xv[j].x); o.y = f2bf(xv[j].y); o.z = f2bf(xv[j].z); o.w = f2bf(xv[j].w);
    *(ushort4*)&xb[(size_t)t * D_DIM + (lane + 64 * j) * 4] = o;
  }
  float acc[E_EXP];
#pragma unroll
  for (int e = 0; e < E_EXP; ++e) {
    const float4* gr = (const float4*)(gw + (size_t)e * D_DIM);
    float a = 0.f;
#pragma unroll
    for (int j = 0; j < 4; ++j) {
      float4 g = gr[lane + 64 * j];
      a += xv[j].x * g.x + xv[j].y * g.y + xv[j].z * g.z + xv[j].w * g.w;
    }
    acc[e] = a;
  }
#pragma unroll
  for (int off = 32; off; off >>= 1)
#pragma unroll
    for (int e = 0; e < E_EXP; ++e) acc[e] += __shfl_xor(acc[e], off, 64);
  if (lane == 0) {
    int i0 = 0; float m0 = acc[0];
#pragma unroll
    for (int e = 1; e < E_EXP; ++e) if (acc[e] > m0) { m0 = acc[e]; i0 = e; }
    int i1 = -1; float m1 = -1e30f;
#pragma unroll
    for (int e = 0; e < E_EXP; ++e) if (e != i0 && acc[e] > m1) { m1 = acc[e]; i1 = e; }
    float e1 = __expf(m1 - m0);
    float w0 = 1.0f / (1.0f + e1);
    float w1 = e1 / (1.0f + e1);
    topk_idx[2 * t] = i0; topk_idx[2 * t + 1] = i1;
    topk_w[2 * t] = w0;   topk_w[2 * t + 1] = w1;
  }
}

// ---------------- 3) route: counts+offsets+meta+perm+inv, zero atomics --------
__global__ __launch_bounds__(1024) void route_kernel(
    const int* __restrict__ tidx, int* __restrict__ meta,
    int* __restrict__ perm, int* __restrict__ inv) {
  __shared__ int els[NPAIR];            // 32 KB
  __shared__ int cnt_iw[128][E_EXP];
  __shared__ int base_iw[128][E_EXP];
  __shared__ int ebase[E_EXP];
  __shared__ int ecnt[E_EXP];
  int tid = threadIdx.x, lane = tid & 63, wv = tid >> 6;   // 16 waves

  for (int it = 0; it < NPAIR / 1024; ++it) {              // 8 iters
    int g = it * 1024 + tid;
    int e = tidx[g];
    els[g] = e;
#pragma unroll
    for (int ex = 0; ex < E_EXP; ++ex) {
      unsigned long long m = __ballot(e == ex);
      if (lane == 0) cnt_iw[it * 16 + wv][ex] = __popcll(m);
    }
  }
  __syncthreads();

  if (tid < E_EXP) {
    int s = 0;
    for (int iw = 0; iw < 128; ++iw) { base_iw[iw][tid] = s; s += cnt_iw[iw][tid]; }
    ecnt[tid] = s;
  }
  __syncthreads();

  if (tid == 0) {
    int o = 0, tc = 0;
    int2* m2 = (int2*)meta;
    for (int e = 0; e < E_EXP; ++e) {
      ebase[e] = o;
      int c = ecnt[e];
      int pt = (c + 127) >> 7;
      for (int ti = 0; ti < pt; ++ti) m2[tc++] = make_int2(e, o + ti * 128);
      o += pt * 128;
    }
    for (int ti = 0; ti < T_TOK / 128; ++ti)
      m2[tc++] = make_int2(E_EXP, SHARED_BASE + ti * 128);
    for (; tc < MAXTILES; ++tc) m2[tc] = make_int2(-1, 0);
  }
  __syncthreads();

  for (int it = 0; it < NPAIR / 1024; ++it) {
    int g = it * 1024 + tid;
    int e = els[g];
    int rank = 0;
#pragma unroll
    for (int ex = 0; ex < E_EXP; ++ex) {
      unsigned long long m = __ballot(e == ex);
      if (e == ex) rank = __popcll(m & ((1ull << lane) - 1ull));
    }
    int row = ebase[e] + base_iw[it * 16 + wv][e] + rank;
    perm[row] = g >> 1;
    inv[g] = row;
  }
  {
    int p = tid;                                           // E_EXP*128 == 1024
    int e = p >> 7, s = p & 127;
    int c = ecnt[e];
    int padn = (((c + 127) >> 7) << 7) - c;
    if (s < padn) perm[ebase[e] + c + s] = 0;
  }
  for (int t = tid; t < T_TOK; t += 1024) perm[SHARED_BASE + t] = t;
}

// -------- 4) GEMM1: dbuf 2-phase, counted vmcnt, XOR-swizzled LDS ---------
__global__ __launch_bounds__(256, 2) void gemm1_kernel(
    const unsigned short* __restrict__ xb, const unsigned short* __restrict__ UG,
    const unsigned short* __restrict__ sUG, unsigned short* __restrict__ H,
    const int* __restrict__ meta, const int* __restrict__ perm) {
  int orig = blockIdx.x;
  int wg = (orig & 7) * (GRID_G / 8) + (orig >> 3);  // XCD chunk swizzle (bijective)
  int mt = wg >> 3, nt = wg & 7;
  int2 m2 = ((const int2*)meta)[mt];
  int e = m2.x;
  if (e < 0) return;
  int base = m2.y;
  int n0 = nt * 128;
  const unsigned short* B = (e < E_EXP) ? UG + (size_t)e * 2 * I_DIM * D_DIM : sUG;

  __shared__ unsigned short As[2 * 128 * 64];   // 32 KB x2 buf halves (A)
  __shared__ unsigned short Bs[2 * 128 * 64];

  int tid = threadIdx.x, lane = tid & 63, wv = tid >> 6;
  // staging: 1024 16B-chunks per array, 4 per thread. chunk c: row=c>>3, q=c&7.
  // source k-offset swizzled by row (qs = q ^ (row&7)); LDS dest stays linear.
  const unsigned short *gA[4], *gB[4];
  int dL[4];
#pragma unroll
  for (int j = 0; j < 4; ++j) {
    int c = j * 256 + tid;
    int row = c >> 3, q = c & 7, qs = q ^ (row & 7);
    int tok = perm[base + row];
    gA[j] = xb + (size_t)tok * D_DIM + qs * 8;
    gB[j] = B + (size_t)(n0 + row) * D_DIM + qs * 8;
    dL[j] = (j * 256 + wv * 64) * 8;             // wave-uniform 16B-linear dest
  }

  f32x4 acc[4][4] = {};
  int wr = (wv >> 1) * 64, wc = (wv & 1) * 64;
  int l15 = lane & 15, l4 = lane >> 4;
  int sx = l15 & 7;                                  // read-side XOR term

#define STAGE1(buf, k0) do { \
  _Pragma("unroll") \
  for (int j = 0; j < 4; ++j) { \
    gload_lds16(gA[j] + (k0), As + (buf) * 8192 + dL[j]); \
    gload_lds16(gB[j] + (k0), Bs + (buf) * 8192 + dL[j]); \
  } } while (0)

  STAGE1(0, 0);                                    // prologue
  const int NK = D_DIM / 64;                       // 16
  for (int t = 0; t < NK; ++t) {
    int cur = t & 1;
    if (t + 1 < NK) {
      STAGE1(cur ^ 1, (t + 1) * 64);
      asm volatile("s_waitcnt vmcnt(8)" ::: "memory");   // only cur's 8 loads
    } else {
      asm volatile("s_waitcnt vmcnt(0)" ::: "memory");
    }
    __builtin_amdgcn_s_barrier();                  // buf[cur] visible to all
    bf16x8 af[2][4], bfr[2][4];
#pragma unroll
    for (int kh = 0; kh < 2; ++kh) {
      int kb = kh * 4 + l4;
#pragma unroll
      for (int i = 0; i < 4; ++i) {
        af[kh][i]  = *reinterpret_cast<const bf16x8*>(&As[cur * 8192 + (wr + i * 16 + l15) * 64 + (kb ^ sx) * 8]);
        bfr[kh][i] = *reinterpret_cast<const bf16x8*>(&Bs[cur * 8192 + (wc + i * 16 + l15) * 64 + (kb ^ sx) * 8]);
      }
    }
    asm volatile("" ::: "memory");
    __builtin_amdgcn_s_barrier();                  // reads done -> next stage safe
    __builtin_amdgcn_s_setprio(1);
#pragma unroll
    for (int kh = 0; kh < 2; ++kh)
#pragma unroll
      for (int i = 0; i < 4; ++i)
#pragma unroll
        for (int j = 0; j < 4; ++j)
          acc[i][j] = __builtin_amdgcn_mfma_f32_16x16x32_bf16(af[kh][i], bfr[kh][j], acc[i][j], 0, 0, 0);
    __builtin_amdgcn_s_setprio(0);
  }
#undef STAGE1

  // epilogue: frag 2m = U, frag 2m+1 = G for the same logical H column block
  const float is2 = 0.70710678118654752f;
  int hbase = (n0 >> 1) + (wv & 1) * 32;
#pragma unroll
  for (int i = 0; i < 4; ++i) {
    int row = base + wr + i * 16 + l4 * 4;
#pragma unroll
    for (int m = 0; m < 2; ++m) {
      int col = hbase + m * 16 + l15;
#pragma unroll
      for (int r = 0; r < 4; ++r) {
        float u = acc[i][2 * m][r], g = acc[i][2 * m + 1][r];
        float gl = 0.5f * g * (1.0f + erff(g * is2));
        H[(size_t)(row + r) * I_DIM + col] = f2bf(u * gl);
      }
    }
  }
}

// -------- 5) GEMM2: Y = H @ Down, dbuf 2-phase, counted vmcnt ---------
__global__ __launch_bounds__(256, 2) void gemm2_kernel(
    const unsigned short* __restrict__ H, const unsigned short* __restrict__ Dt,
    const unsigned short* __restrict__ sDt, unsigned short* __restrict__ Y,
    const int* __restrict__ meta) {
  int orig = blockIdx.x;
  int wg = (orig & 7) * (GRID_G / 8) + (orig >> 3);
  int mt = wg >> 3, nt = wg & 7;
  int2 m2 = ((const int2*)meta)[mt];
  int e = m2.x;
  if (e < 0) return;
  int base = m2.y;
  int n0 = nt * 128;
  const unsigned short* B = (e < E_EXP) ? Dt + (size_t)e * D_DIM * I_DIM : sDt;

  __shared__ unsigned short As[2 * 128 * 64];
  __shared__ unsigned short Bs[2 * 128 * 64];

  int tid = threadIdx.x, lane = tid & 63, wv = tid >> 6;
  const unsigned short *gA[4], *gB[4];
  int dL[4];
#pragma unroll
  for (int j = 0; j < 4; ++j) {
    int c = j * 256 + tid;
    int row = c >> 3, q = c & 7, qs = q ^ (row & 7);
    gA[j] = H + (size_t)(base + row) * I_DIM + qs * 8;
    gB[j] = B + (size_t)(n0 + row) * I_DIM + qs * 8;
    dL[j] = (j * 256 + wv * 64) * 8;
  }

  f32x4 acc[4][4] = {};
  int wr = (wv >> 1) * 64, wc = (wv & 1) * 64;
  int l15 = lane & 15, l4 = lane >> 4;
  int sx = l15 & 7;

#define STAGE2(buf, k0) do { \
  _Pragma("unroll") \
  for (int j = 0; j < 4; ++j) { \
    gload_lds16(gA[j] + (k0), As + (buf) * 8192 + dL[j]); \
    gload_lds16(gB[j] + (k0), Bs + (buf) * 8192 + dL[j]); \
  } } while (0)

  STAGE2(0, 0);
  const int NK = I_DIM / 64;                       // 8
  for (int t = 0; t < NK; ++t) {
    int cur = t & 1;
    if (t + 1 < NK) {
      STAGE2(cur ^ 1, (t + 1) * 64);
      asm volatile("s_waitcnt vmcnt(8)" ::: "memory");
    } else {
      asm volatile("s_waitcnt vmcnt(0)" ::: "memory");
    }
    __builtin_amdgcn_s_barrier();
    bf16x8 af[2][4], bfr[2][4];
#pragma unroll
    for (int kh = 0; kh < 2; ++kh) {
      int kb = kh * 4 + l4;
#pragma unroll
      for (int i = 0; i < 4; ++i) {
        af[kh][i]  = *reinterpret_cast<const bf16x8*>(&As[cur * 8192 + (wr + i * 16 + l15) * 64 + (kb ^ sx) * 8]);
        bfr[kh][i] = *reinterpret_cast<const bf16x8*>(&Bs[cur * 8192 + (wc + i * 16 + l15) * 64 + (kb ^ sx) * 8]);
      }
    }
    asm volatile("" ::: "memory");
    __builtin_amdgcn_s_barrier();
    __builtin_amdgcn_s_setprio(1);
#pragma unroll
    for (int kh = 0; kh < 2; ++kh)
#pragma unroll
      for (int i = 0; i < 4; ++i)
#pragma unroll
        for (int j = 0; j < 4; ++j)
          acc[i][j] = __builtin_amdgcn_mfma_f32_16x16x32_bf16(af[kh][i], bfr[kh][j], acc[i][j], 0, 0, 0);
    __builtin_amdgcn_s_setprio(0);
  }
#undef STAGE2

#pragma unroll
  for (int i = 0; i < 4; ++i) {
    int row = base + wr + i * 16 + l4 * 4;
#pragma unroll
    for (int j = 0; j < 4; ++j) {
      int col = n0 + wc + j * 16 + l15;
#pragma unroll
      for (int r = 0; r < 4; ++r)
        Y[(size_t)(row + r) * D_DIM + col] = f2bf(acc[i][j][r]);
    }
  }
}

// ---------------- 6) combine: out = w0*Y[r0] + w1*Y[r1] + Y[shared] ----------------
__global__ void combine_kernel(const unsigned short* __restrict__ Y, const int* __restrict__ inv,
                               const float* __restrict__ tw, float* __restrict__ out) {
  int g = blockIdx.x * 256 + threadIdx.x;
  int t = g >> 7, d0 = (g & 127) * 8;
  int r0 = inv[2 * t], r1 = inv[2 * t + 1];
  float w0 = tw[2 * t], w1 = tw[2 * t + 1];
  ushort8 y0 = *(const ushort8*)&Y[(size_t)r0 * D_DIM + d0];
  ushort8 y1 = *(const ushort8*)&Y[(size_t)r1 * D_DIM + d0];
  ushort8 ys = *(const ushort8*)&Y[(size_t)(SHARED_BASE + t) * D_DIM + d0];
  float o[8];
#pragma unroll
  for (int j = 0; j < 8; ++j)
    o[j] = w0 * bf2f(y0[j]) + w1 * bf2f(y1[j]) + bf2f(ys[j]);
  float4* op = (float4*)(out + (size_t)t * D_DIM + d0);
  op[0] = make_float4(o[0], o[1], o[2], o[3]);
  op[1] = make_float4(o[4], o[5], o[6], o[7]);
}

// ---------------- launcher ----------------
extern "C" void kernel_launch(void* const* d_in, const int* in_sizes, int n_in,
                              void* d_out, int out_size, void* d_ws, size_t ws_size,
                              hipStream_t stream) {
  const float* x    = (const float*)d_in[0];
  const float* gw   = (const float*)d_in[1];
  const float* upw  = (const float*)d_in[2];
  const float* gpw  = (const float*)d_in[3];
  const float* dww  = (const float*)d_in[4];
  const float* sup  = (const float*)d_in[5];
  const float* sgt  = (const float*)d_in[6];
  const float* sdw  = (const float*)d_in[7];
  float* out = (float*)d_out;

  char* ws = (char*)d_ws;
  unsigned short* xb  = (unsigned short*)(ws + OFF_XB);
  unsigned short* UG  = (unsigned short*)(ws + OFF_UG);
  unsigned short* Dt  = (unsigned short*)(ws + OFF_DT);
  unsigned short* sUG = (unsigned short*)(ws + OFF_SUG);
  unsigned short* sDt = (unsigned short*)(ws + OFF_SDT);
  unsigned short* H   = (unsigned short*)(ws + OFF_H);
  unsigned short* Y   = (unsigned short*)(ws + OFF_Y);
  int*   tki   = (int*)(ws + OFF_TOPKI);
  float* tkw   = (float*)(ws + OFF_TOPKW);
  int*   inv   = (int*)(ws + OFF_INV);
  int*   perm  = (int*)(ws + OFF_PERM);
  int*   meta  = (int*)(ws + OFF_META);

  transpose_cvt_all<<<13824, dim3(32, 8), 0, stream>>>(upw, gpw, dww, sup, sgt, sdw,
                                                       UG, sUG, Dt, sDt);
  gating_kernel<<<T_TOK / 4, 256, 0, stream>>>(x, gw, xb, tki, tkw);
  route_kernel<<<1, 1024, 0, stream>>>(tki, meta, perm, inv);

  gemm1_kernel<<<GRID_G, 256, 0, stream>>>(xb, UG, sUG, H, meta, perm);
  gemm2_kernel<<<GRID_G, 256, 0, stream>>>(H, Dt, sDt, Y, meta);
  combine_kernel<<<(T_TOK * 128) / 256, 256, 0, stream>>>(Y, inv, tkw, out);
}